// Round 6
// baseline (1402.804 us; speedup 1.0000x reference)
//
#include <hip/hip_runtime.h>
#include <hip/hip_bf16.h>

#define NN 50000
#define NE 800000
#define EPSV 1e-5f
#define NB 49   // scan blocks: ceil(NN/1024)

typedef _Float16 h8 __attribute__((ext_vector_type(8)));
typedef float    f4 __attribute__((ext_vector_type(4)));

// ---------------- graph preprocessing ----------------

__global__ void k_deg(const int* __restrict__ dst, int* __restrict__ deg){
  int e = blockIdx.x*blockDim.x + threadIdx.x;
  if(e < NE) atomicAdd(&deg[dst[e]], 1);
}

__global__ void k_logdeg(const int* __restrict__ deg, float* __restrict__ logdeg,
                         float* __restrict__ dsum){
  int i = blockIdx.x*blockDim.x + threadIdx.x;
  float v = 0.f;
  if(i < NN){ v = log1pf((float)deg[i]); logdeg[i] = v; }
  __shared__ float sh[256];
  sh[threadIdx.x] = v; __syncthreads();
  for(int off=128; off>0; off>>=1){
    if(threadIdx.x < off) sh[threadIdx.x] += sh[threadIdx.x+off];
    __syncthreads();
  }
  if(threadIdx.x == 0) atomicAdd(dsum, sh[0]);
}

__global__ void k_scalers(const float* __restrict__ logdeg, const float* __restrict__ dsum,
                          float* __restrict__ amp, float* __restrict__ att){
  int i = blockIdx.x*blockDim.x + threadIdx.x;
  if(i >= NN) return;
  float delta = dsum[0] / (float)NN;
  float ld = logdeg[i];
  amp[i] = ld / delta;
  att[i] = (ld > 0.f) ? (delta / fmaxf(ld, 1e-6f)) : 1.f;
}

// 3-phase parallel exclusive scan of deg -> rowptr (+cursor copy)
__global__ void k_scan1(const int* __restrict__ deg, int* __restrict__ rowptr,
                        int* __restrict__ bsum){
  __shared__ int buf[1024];
  int tid = threadIdx.x;
  int i = blockIdx.x*1024 + tid;
  int v = (i < NN) ? deg[i] : 0;
  buf[tid] = v; __syncthreads();
  for(int off=1; off<1024; off<<=1){
    int t = (tid >= off) ? buf[tid-off] : 0;
    __syncthreads();
    buf[tid] += t;
    __syncthreads();
  }
  if(i < NN) rowptr[i] = buf[tid] - v;     // block-local exclusive
  if(tid == 1023) bsum[blockIdx.x] = buf[1023];
}

__global__ void k_scan2(int* __restrict__ bsum){
  if(threadIdx.x == 0){
    int s = 0;
    for(int b = 0; b < NB; b++){ int t = bsum[b]; bsum[b] = s; s += t; }
    bsum[NB] = s;
  }
}

__global__ void k_scan3(int* __restrict__ rowptr, int* __restrict__ cursor,
                        const int* __restrict__ bsum){
  int i = blockIdx.x*256 + threadIdx.x;
  if(i < NN){
    int v = rowptr[i] + bsum[i >> 10];
    rowptr[i] = v; cursor[i] = v;
  }
  if(i == NN) rowptr[NN] = bsum[NB];
}

__global__ void k_fill(const int* __restrict__ src, const int* __restrict__ dst,
                       int* __restrict__ cursor, int* __restrict__ colidx){
  int e = blockIdx.x*blockDim.x + threadIdx.x;
  if(e < NE){
    int pos = atomicAdd(&cursor[dst[e]], 1);
    colidx[pos] = src[e];
  }
}

__global__ void k_cvtx(const float* __restrict__ x, _Float16* __restrict__ hA){
  int i = blockIdx.x*256 + threadIdx.x;
  if(i < NN*64) hA[i] = (_Float16)x[i];
}

// ---------------- chunked per-node aggregation (fp16 in/out, fp32 math) ----------------
// features [j0, j0+64) of h[N,d] -> aggsC[N][4*64] = mean|min|max|std
// 256 threads = 4 waves = 4 nodes per block.

__global__ __launch_bounds__(256) void k_agg_chunk(
    const _Float16* __restrict__ h, int d, int j0,
    const int* __restrict__ rowptr, const int* __restrict__ colidx,
    _Float16* __restrict__ aggsC){
  int n = blockIdx.x*4 + (threadIdx.x >> 6);
  int j = threadIdx.x & 63;
  if(n >= NN) return;
  int beg = rowptr[n], end = rowptr[n+1];
  float s = 0.f, ss = 0.f, mn = INFINITY, mx = -INFINITY;
  for(int e = beg; e < end; e++){
    int sidx = colidx[e];
    float v = (float)h[(size_t)sidx*d + j0 + j];
    s += v; ss += v*v;
    mn = fminf(mn, v); mx = fmaxf(mx, v);
  }
  float cnt  = (end > beg) ? (float)(end - beg) : 1.f;
  float mean = s / cnt;
  float msq  = ss / cnt;
  float sd   = sqrtf(fmaxf(msq - mean*mean, 0.f) + EPSV);
  if(end <= beg){ mn = 0.f; mx = 0.f; }
  size_t base = (size_t)n * 256;
  aggsC[base + j]       = (_Float16)mean;
  aggsC[base + 64 + j]  = (_Float16)mn;
  aggsC[base + 128 + j] = (_Float16)mx;
  aggsC[base + 192 + j] = (_Float16)sd;
}

// ---------------- fused W pre-pack (all layers/chunks, one kernel) ----------------
// Per (layer,chunk): Wp[kb=K/32][nt=o/16][lane=64][j=8], k=kb*32+(lane>>4)*8+j,
// n=nt*16+(lane&15); row perm: k<64 -> j0+k ; [64,320) -> (1+q)d+j0+r ;
// [320,576) -> (5+q)d+j0+r ; [576,832) -> (9+q)d+j0+r  (q=t>>6, r=t&63)

struct PackJob { const float* W; _Float16* dst; int d, o, j0, start; };
struct PackArgs { PackJob job[9]; int total; };

__global__ void k_pack_all(PackArgs a){
  int idx = blockIdx.x*256 + threadIdx.x;
  if(idx >= a.total) return;
  int ji = 0;
  while(ji < 8 && idx >= a.job[ji+1].start) ji++;
  PackJob J = a.job[ji];
  int rel = idx - J.start;
  int j    = rel & 7;
  int lane = (rel >> 3) & 63;
  int rem  = rel >> 9;
  int ntiles = J.o >> 4;
  int kb = rem / ntiles;
  int nt = rem - kb*ntiles;
  int k = kb*32 + (lane>>4)*8 + j;
  int n = nt*16 + (lane&15);
  int srcrow;
  if(k < 64)       srcrow = J.j0 + k;
  else if(k < 320){ int t=k-64;  srcrow = (1+(t>>6))*J.d + J.j0 + (t&63); }
  else if(k < 576){ int t=k-320; srcrow = (5+(t>>6))*J.d + J.j0 + (t&63); }
  else            { int t=k-576; srcrow = (9+(t>>6))*J.d + J.j0 + (t&63); }
  J.dst[rel] = (_Float16)J.W[(size_t)srcrow*J.o + n];
}

// ---------------- MFMA chunked GEMM ----------------
// hB[m,0:o] (+)= virtualA[m,0:832] @ Wp  (+bias on init)
// virtualA = [ hA[m,j0:j0+64] | aggsC[m,:] | amp[m]*aggsC | att[m]*aggsC ]
// 256 thr = 4 waves; tile 128(M) x 64(N); no LDS/barriers; A fp16 direct loads.

__global__ __launch_bounds__(256) void k_mfma(
    const _Float16* __restrict__ hA, int d, int j0,
    const _Float16* __restrict__ aggsC,
    const float* __restrict__ amp, const float* __restrict__ att,
    const _Float16* __restrict__ Wp, int o,
    const float* __restrict__ bias,
    float* __restrict__ hB, int init)
{
  int tid  = threadIdx.x;
  int w    = tid >> 6;
  int lane = tid & 63;
  int mi   = lane & 15;      // A row / D col
  int q    = lane >> 4;      // k-quad / D row-quad
  int m0   = blockIdx.y * 128 + w * 32;
  int c0   = blockIdx.x * 64;
  int ntiles = o >> 4;
  int nt0  = blockIdx.x * 4;

  int mrow[2];
  mrow[0] = min(m0 + mi,      NN-1);
  mrow[1] = min(m0 + 16 + mi, NN-1);
  _Float16 am16[2] = { (_Float16)amp[mrow[0]], (_Float16)amp[mrow[1]] };
  _Float16 at16[2] = { (_Float16)att[mrow[0]], (_Float16)att[mrow[1]] };
  const _Float16* hAp[2];
  const _Float16* agp[2];
  hAp[0] = hA + (size_t)mrow[0]*d + j0 + q*8;
  hAp[1] = hA + (size_t)mrow[1]*d + j0 + q*8;
  agp[0] = aggsC + (size_t)mrow[0]*256 + q*8;
  agp[1] = aggsC + (size_t)mrow[1]*256 + q*8;

  f4 acc[2][4] = {};

  auto bfrag = [&](int kb, int nn) -> h8 {
    return *(const h8*)(Wp + (((size_t)kb*ntiles + nt0 + nn)*64 + lane)*8);
  };

  // ---- phase X: hA chunk, kb = 0,1 ----
  #pragma unroll
  for(int kb = 0; kb < 2; kb++){
    h8 a[2];
    #pragma unroll
    for(int t = 0; t < 2; t++) a[t] = *(const h8*)(hAp[t] + kb*32);
    #pragma unroll
    for(int t = 0; t < 2; t++)
      #pragma unroll
      for(int nn = 0; nn < 4; nn++)
        acc[t][nn] = __builtin_amdgcn_mfma_f32_16x16x32_f16(a[t], bfrag(kb,nn), acc[t][nn], 0,0,0);
  }

  // ---- aggs phases: one load, three packed-scale variants ----
  #pragma unroll 2
  for(int kb2 = 0; kb2 < 8; kb2++){
    h8 apl[2], aam[2], aat[2];
    #pragma unroll
    for(int t = 0; t < 2; t++){
      apl[t] = *(const h8*)(agp[t] + kb2*32);
      aam[t] = apl[t] * am16[t];
      aat[t] = apl[t] * at16[t];
    }
    #pragma unroll
    for(int t = 0; t < 2; t++){
      #pragma unroll
      for(int nn = 0; nn < 4; nn++){
        acc[t][nn] = __builtin_amdgcn_mfma_f32_16x16x32_f16(apl[t], bfrag(2+kb2,  nn), acc[t][nn], 0,0,0);
        acc[t][nn] = __builtin_amdgcn_mfma_f32_16x16x32_f16(aam[t], bfrag(10+kb2, nn), acc[t][nn], 0,0,0);
        acc[t][nn] = __builtin_amdgcn_mfma_f32_16x16x32_f16(aat[t], bfrag(18+kb2, nn), acc[t][nn], 0,0,0);
      }
    }
  }

  // ---- epilogue: D col = lane&15, row = q*4 + reg ----
  #pragma unroll
  for(int t = 0; t < 2; t++){
    #pragma unroll
    for(int nn = 0; nn < 4; nn++){
      int n = c0 + nn*16 + mi;
      #pragma unroll
      for(int r = 0; r < 4; r++){
        int m = m0 + t*16 + q*4 + r;
        if(m < NN){
          float* cp = hB + (size_t)m*o + n;
          float base = init ? bias[n] : *cp;
          *cp = base + acc[t][nn][r];
        }
      }
    }
  }
}

// ---------------- ReLU + BatchNorm ----------------

__global__ __launch_bounds__(256) void k_bn_stats(const float* __restrict__ H, int dout,
                                                  float* __restrict__ colsum, float* __restrict__ colss){
  int tid = threadIdx.x;
  int gid = blockIdx.x*256 + tid;
  int stride = gridDim.x*256;
  int total = NN * dout;
  float s = 0.f, ss = 0.f;
  for(int i = gid; i < total; i += stride){
    float v = fmaxf(H[i], 0.f);
    s += v; ss += v*v;
  }
  __shared__ float shs[256], shss[256];
  shs[tid] = s; shss[tid] = ss;
  __syncthreads();
  if(tid < dout){
    float ts = 0.f, tss = 0.f;
    for(int i = tid; i < 256; i += dout){ ts += shs[i]; tss += shss[i]; }
    atomicAdd(&colsum[tid], ts);
    atomicAdd(&colss[tid], tss);
  }
}

__global__ void k_bn_apply(const float* __restrict__ H, int dout,
                           const float* __restrict__ colsum, const float* __restrict__ colss,
                           const float* __restrict__ gamma, const float* __restrict__ beta,
                           _Float16* __restrict__ out){
  int i = blockIdx.x*blockDim.x + threadIdx.x;
  int total = NN * dout;
  if(i >= total) return;
  int c = i & (dout - 1);
  float mean = colsum[c] / (float)NN;
  float var  = colss[c] / (float)NN - mean*mean;
  float inv  = rsqrtf(fmaxf(var, 0.f) + EPSV);
  float v = fmaxf(H[i], 0.f);
  out[i] = (_Float16)((v - mean) * inv * gamma[c] + beta[c]);
}

// ---------------- classifier ----------------

__global__ __launch_bounds__(256) void k_cls(const _Float16* __restrict__ h,
    const float* __restrict__ Wc, const float* __restrict__ bc,
    float* __restrict__ out){
  __shared__ float w[640];
  __shared__ float bb[16];
  int tid = threadIdx.x;
  for(int i = tid; i < 640; i += 256) w[i] = Wc[i];
  if(tid < 10) bb[tid] = bc[tid];
  __syncthreads();
  int idx = blockIdx.x*256 + tid;
  int n = idx >> 4;
  int c = idx & 15;
  if(n < NN && c < 10){
    float acc = bb[c];
    const _Float16* hp = h + (size_t)n*64;
    #pragma unroll
    for(int k = 0; k < 64; k++) acc += (float)hp[k] * w[k*10 + c];
    out[(size_t)n*10 + c] = acc;
  }
}

// ---------------- launch ----------------

extern "C" void kernel_launch(void* const* d_in, const int* in_sizes, int n_in,
                              void* d_out, int out_size, void* d_ws, size_t ws_size,
                              hipStream_t stream){
  const float* x = (const float*)d_in[0];
  const int* edge = (const int*)d_in[1];
  const int* esrc = edge;
  const int* edst = edge + NE;
  const float* W[4]  = {(const float*)d_in[2],  (const float*)d_in[6],
                        (const float*)d_in[10], (const float*)d_in[14]};
  const float* bb[4] = {(const float*)d_in[3],  (const float*)d_in[7],
                        (const float*)d_in[11], (const float*)d_in[15]};
  const float* gm[4] = {(const float*)d_in[4],  (const float*)d_in[8],
                        (const float*)d_in[12], (const float*)d_in[16]};
  const float* bt[4] = {(const float*)d_in[5],  (const float*)d_in[9],
                        (const float*)d_in[13], (const float*)d_in[17]};
  const float* Wc = (const float*)d_in[18];
  const float* bc = (const float*)d_in[19];
  (void)in_sizes; (void)n_in; (void)out_size; (void)ws_size;

  // workspace carve (~130 MB)
  char* p = (char*)d_ws;
  auto alloc = [&](size_t bytes)->char*{
    char* r = p; p += (bytes + 255) & ~(size_t)255; return r;
  };
  _Float16* hA    = (_Float16*)alloc((size_t)NN*256*2);  // 25.6 MB
  float*    hB    = (float*)   alloc((size_t)NN*256*4);  // 51.2 MB
  _Float16* aggsC = (_Float16*)alloc((size_t)NN*256*2);  // 25.6 MB
  int*   deg    = (int*)  alloc((size_t)NN*4);
  float* logdeg = (float*)alloc((size_t)NN*4);
  float* amp    = (float*)alloc((size_t)NN*4);
  float* att    = (float*)alloc((size_t)NN*4);
  int*   rowptr = (int*)  alloc((size_t)(NN+1)*4);
  int*   cursor = (int*)  alloc((size_t)NN*4);
  int*   colidx = (int*)  alloc((size_t)NE*4);
  int*   bsum   = (int*)  alloc((size_t)(NB+1)*4);
  float* colsum = (float*)alloc(256*4);
  float* colss  = (float*)alloc(256*4);
  float* dsum   = (float*)alloc(256);

  const int din[4]  = {64, 128, 256, 128};
  const int dto[4]  = {128, 256, 128, 64};
  _Float16* Wp[4][4];
  PackArgs pa; int pj = 0, poff = 0;
  for(int l = 0; l < 4; l++)
    for(int c = 0; c < din[l]/64; c++){
      Wp[l][c] = (_Float16*)alloc((size_t)832*dto[l]*2);
      pa.job[pj] = { W[l], Wp[l][c], din[l], dto[l], c*64, poff };
      poff += 832*dto[l]; pj++;
    }
  pa.total = poff;

  hipMemsetAsync(deg, 0, (size_t)NN*4, stream);
  hipMemsetAsync(dsum, 0, 4, stream);

  k_pack_all<<<(pa.total+255)/256, 256, 0, stream>>>(pa);
  k_deg     <<<(NE+255)/256, 256, 0, stream>>>(edst, deg);
  k_logdeg  <<<(NN+255)/256, 256, 0, stream>>>(deg, logdeg, dsum);
  k_scalers <<<(NN+255)/256, 256, 0, stream>>>(logdeg, dsum, amp, att);
  k_scan1   <<<NB, 1024, 0, stream>>>(deg, rowptr, bsum);
  k_scan2   <<<1, 64, 0, stream>>>(bsum);
  k_scan3   <<<(NN+256)/256, 256, 0, stream>>>(rowptr, cursor, bsum);
  k_fill    <<<(NE+255)/256, 256, 0, stream>>>(esrc, edst, cursor, colidx);
  k_cvtx    <<<(NN*64+255)/256, 256, 0, stream>>>(x, hA);

  for(int l = 0; l < 4; l++){
    int d = din[l], o = dto[l];
    int nch = d / 64;
    dim3 g(o/64, (NN+127)/128);
    for(int c = 0; c < nch; c++){
      int j0 = c*64;
      k_agg_chunk<<<(NN+3)/4, 256, 0, stream>>>(hA, d, j0, rowptr, colidx, aggsC);
      k_mfma<<<g, 256, 0, stream>>>(hA, d, j0, aggsC, amp, att, Wp[l][c], o, bb[l], hB, c==0);
    }
    hipMemsetAsync(colsum, 0, (size_t)o*4, stream);
    hipMemsetAsync(colss,  0, (size_t)o*4, stream);
    k_bn_stats<<<256, 256, 0, stream>>>(hB, o, colsum, colss);
    k_bn_apply<<<(NN*o+255)/256, 256, 0, stream>>>(hB, o, colsum, colss, gm[l], bt[l], hA);
  }
  k_cls<<<(NN*16+255)/256, 256, 0, stream>>>(hA, Wc, bc, (float*)d_out);
}

// Round 7
// 919.453 us; speedup vs baseline: 1.5257x; 1.5257x over previous
//
#include <hip/hip_runtime.h>
#include <hip/hip_bf16.h>

#define NN 50000
#define NE 800000
#define EPSV 1e-5f
#define NB 49   // scan blocks: ceil(NN/1024)

typedef _Float16 h8 __attribute__((ext_vector_type(8)));
typedef _Float16 h2v __attribute__((ext_vector_type(2)));
typedef float    f4 __attribute__((ext_vector_type(4)));

// ---------------- graph preprocessing ----------------

__global__ void k_deg(const int* __restrict__ dst, int* __restrict__ deg){
  int e = blockIdx.x*blockDim.x + threadIdx.x;
  if(e < NE) atomicAdd(&deg[dst[e]], 1);
}

__global__ void k_logdeg(const int* __restrict__ deg, float* __restrict__ logdeg,
                         float* __restrict__ dsum){
  int i = blockIdx.x*blockDim.x + threadIdx.x;
  float v = 0.f;
  if(i < NN){ v = log1pf((float)deg[i]); logdeg[i] = v; }
  __shared__ float sh[256];
  sh[threadIdx.x] = v; __syncthreads();
  for(int off=128; off>0; off>>=1){
    if(threadIdx.x < off) sh[threadIdx.x] += sh[threadIdx.x+off];
    __syncthreads();
  }
  if(threadIdx.x == 0) atomicAdd(dsum, sh[0]);
}

__global__ void k_scalers(const float* __restrict__ logdeg, const float* __restrict__ dsum,
                          float* __restrict__ amp, float* __restrict__ att){
  int i = blockIdx.x*blockDim.x + threadIdx.x;
  if(i >= NN) return;
  float delta = dsum[0] / (float)NN;
  float ld = logdeg[i];
  amp[i] = ld / delta;
  att[i] = (ld > 0.f) ? (delta / fmaxf(ld, 1e-6f)) : 1.f;
}

// 3-phase parallel exclusive scan of deg -> rowptr (+cursor copy)
__global__ void k_scan1(const int* __restrict__ deg, int* __restrict__ rowptr,
                        int* __restrict__ bsum){
  __shared__ int buf[1024];
  int tid = threadIdx.x;
  int i = blockIdx.x*1024 + tid;
  int v = (i < NN) ? deg[i] : 0;
  buf[tid] = v; __syncthreads();
  for(int off=1; off<1024; off<<=1){
    int t = (tid >= off) ? buf[tid-off] : 0;
    __syncthreads();
    buf[tid] += t;
    __syncthreads();
  }
  if(i < NN) rowptr[i] = buf[tid] - v;
  if(tid == 1023) bsum[blockIdx.x] = buf[1023];
}

__global__ void k_scan2(int* __restrict__ bsum){
  if(threadIdx.x == 0){
    int s = 0;
    for(int b = 0; b < NB; b++){ int t = bsum[b]; bsum[b] = s; s += t; }
    bsum[NB] = s;
  }
}

__global__ void k_scan3(int* __restrict__ rowptr, int* __restrict__ cursor,
                        const int* __restrict__ bsum){
  int i = blockIdx.x*256 + threadIdx.x;
  if(i < NN){
    int v = rowptr[i] + bsum[i >> 10];
    rowptr[i] = v; cursor[i] = v;
  }
  if(i == NN) rowptr[NN] = bsum[NB];
}

__global__ void k_fill(const int* __restrict__ src, const int* __restrict__ dst,
                       int* __restrict__ cursor, int* __restrict__ colidx){
  int e = blockIdx.x*blockDim.x + threadIdx.x;
  if(e < NE){
    int pos = atomicAdd(&cursor[dst[e]], 1);
    colidx[pos] = src[e];
  }
}

__global__ void k_cvtx(const float* __restrict__ x, _Float16* __restrict__ hA){
  int i = blockIdx.x*256 + threadIdx.x;
  if(i < NN*64) hA[i] = (_Float16)x[i];
}

// ---------------- wide per-node aggregation ----------------
// Covers 128 feature columns (two 64-col chunks) per pass: lane handles 2
// adjacent cols via one 4-B load per edge; 4-way edge unroll for MLP.
// two==1 (d=64): 2 nodes per wave, 64-col chunk, all output to agg0.
// Output layout per 64-col chunk buffer: agg[n*256 + {0,64,128,192} + col]
//  = mean | min | max | std  (matches k_mfma's aggsC addressing).

__global__ __launch_bounds__(256) void k_agg2(
    const _Float16* __restrict__ h, int d, int j0, int two,
    const int* __restrict__ rowptr, const int* __restrict__ colidx,
    _Float16* __restrict__ agg0, _Float16* __restrict__ agg1)
{
  int wv = threadIdx.x >> 6, lane = threadIdx.x & 63;
  int n, c;
  if(two){ n = blockIdx.x*8 + wv*2 + (lane>>5); c = (lane&31)<<1; }
  else   { n = blockIdx.x*4 + wv;               c = lane<<1; }
  if(n >= NN) return;
  int beg = rowptr[n], end = rowptr[n+1];
  const _Float16* hp = h + j0 + c;
  float s0=0.f,s1=0.f,q0=0.f,q1=0.f;
  float mn0=INFINITY,mn1=INFINITY,mx0=-INFINITY,mx1=-INFINITY;

#define ACC2(v) { float a=(float)(v)[0], b=(float)(v)[1]; \
    s0+=a; q0+=a*a; mn0=fminf(mn0,a); mx0=fmaxf(mx0,a); \
    s1+=b; q1+=b*b; mn1=fminf(mn1,b); mx1=fmaxf(mx1,b); }

  int e = beg;
  for(; e+4 <= end; e+=4){
    int i0=colidx[e], i1=colidx[e+1], i2=colidx[e+2], i3=colidx[e+3];
    h2v v0 = *(const h2v*)(hp + (size_t)i0*d);
    h2v v1 = *(const h2v*)(hp + (size_t)i1*d);
    h2v v2 = *(const h2v*)(hp + (size_t)i2*d);
    h2v v3 = *(const h2v*)(hp + (size_t)i3*d);
    ACC2(v0) ACC2(v1) ACC2(v2) ACC2(v3)
  }
  for(; e < end; e++){
    h2v v = *(const h2v*)(hp + (size_t)colidx[e]*d);
    ACC2(v)
  }
#undef ACC2

  float cnt = (end>beg) ? (float)(end-beg) : 1.f;
  float mean0 = s0/cnt, mean1 = s1/cnt;
  float sd0 = sqrtf(fmaxf(q0/cnt - mean0*mean0, 0.f) + EPSV);
  float sd1 = sqrtf(fmaxf(q1/cnt - mean1*mean1, 0.f) + EPSV);
  if(end <= beg){ mn0=0.f; mn1=0.f; mx0=0.f; mx1=0.f; }

  _Float16* dst; int cl;
  if(c < 64){ dst = agg0; cl = c; } else { dst = agg1; cl = c-64; }
  size_t base = (size_t)n*256 + cl;
  h2v o0 = {(_Float16)mean0,(_Float16)mean1};
  h2v o1 = {(_Float16)mn0,(_Float16)mn1};
  h2v o2 = {(_Float16)mx0,(_Float16)mx1};
  h2v o3 = {(_Float16)sd0,(_Float16)sd1};
  *(h2v*)(dst+base)       = o0;
  *(h2v*)(dst+base+64)    = o1;
  *(h2v*)(dst+base+128)   = o2;
  *(h2v*)(dst+base+192)   = o3;
}

// ---------------- fused W pre-pack (all layers/chunks, one kernel) ----------------

struct PackJob { const float* W; _Float16* dst; int d, o, j0, start; };
struct PackArgs { PackJob job[9]; int total; };

__global__ void k_pack_all(PackArgs a){
  int idx = blockIdx.x*256 + threadIdx.x;
  if(idx >= a.total) return;
  int ji = 0;
  while(ji < 8 && idx >= a.job[ji+1].start) ji++;
  PackJob J = a.job[ji];
  int rel = idx - J.start;
  int j    = rel & 7;
  int lane = (rel >> 3) & 63;
  int rem  = rel >> 9;
  int ntiles = J.o >> 4;
  int kb = rem / ntiles;
  int nt = rem - kb*ntiles;
  int k = kb*32 + (lane>>4)*8 + j;
  int n = nt*16 + (lane&15);
  int srcrow;
  if(k < 64)       srcrow = J.j0 + k;
  else if(k < 320){ int t=k-64;  srcrow = (1+(t>>6))*J.d + J.j0 + (t&63); }
  else if(k < 576){ int t=k-320; srcrow = (5+(t>>6))*J.d + J.j0 + (t&63); }
  else            { int t=k-576; srcrow = (9+(t>>6))*J.d + J.j0 + (t&63); }
  J.dst[rel] = (_Float16)J.W[(size_t)srcrow*J.o + n];
}

// ---------------- MFMA chunked GEMM ----------------
// hB[m,0:o] (+)= virtualA[m,0:832] @ Wp  (+bias on init)
// virtualA = [ hA[m,j0:j0+64] | aggsC[m,:] | amp[m]*aggsC | att[m]*aggsC ]

__global__ __launch_bounds__(256) void k_mfma(
    const _Float16* __restrict__ hA, int d, int j0,
    const _Float16* __restrict__ aggsC,
    const float* __restrict__ amp, const float* __restrict__ att,
    const _Float16* __restrict__ Wp, int o,
    const float* __restrict__ bias,
    float* __restrict__ hB, int init)
{
  int tid  = threadIdx.x;
  int w    = tid >> 6;
  int lane = tid & 63;
  int mi   = lane & 15;
  int q    = lane >> 4;
  int m0   = blockIdx.y * 128 + w * 32;
  int c0   = blockIdx.x * 64;
  int ntiles = o >> 4;
  int nt0  = blockIdx.x * 4;

  int mrow[2];
  mrow[0] = min(m0 + mi,      NN-1);
  mrow[1] = min(m0 + 16 + mi, NN-1);
  _Float16 am16[2] = { (_Float16)amp[mrow[0]], (_Float16)amp[mrow[1]] };
  _Float16 at16[2] = { (_Float16)att[mrow[0]], (_Float16)att[mrow[1]] };
  const _Float16* hAp[2];
  const _Float16* agp[2];
  hAp[0] = hA + (size_t)mrow[0]*d + j0 + q*8;
  hAp[1] = hA + (size_t)mrow[1]*d + j0 + q*8;
  agp[0] = aggsC + (size_t)mrow[0]*256 + q*8;
  agp[1] = aggsC + (size_t)mrow[1]*256 + q*8;

  f4 acc[2][4] = {};

  auto bfrag = [&](int kb, int nn) -> h8 {
    return *(const h8*)(Wp + (((size_t)kb*ntiles + nt0 + nn)*64 + lane)*8);
  };

  #pragma unroll
  for(int kb = 0; kb < 2; kb++){
    h8 a[2];
    #pragma unroll
    for(int t = 0; t < 2; t++) a[t] = *(const h8*)(hAp[t] + kb*32);
    #pragma unroll
    for(int t = 0; t < 2; t++)
      #pragma unroll
      for(int nn = 0; nn < 4; nn++)
        acc[t][nn] = __builtin_amdgcn_mfma_f32_16x16x32_f16(a[t], bfrag(kb,nn), acc[t][nn], 0,0,0);
  }

  #pragma unroll 2
  for(int kb2 = 0; kb2 < 8; kb2++){
    h8 apl[2], aam[2], aat[2];
    #pragma unroll
    for(int t = 0; t < 2; t++){
      apl[t] = *(const h8*)(agp[t] + kb2*32);
      aam[t] = apl[t] * am16[t];
      aat[t] = apl[t] * at16[t];
    }
    #pragma unroll
    for(int t = 0; t < 2; t++){
      #pragma unroll
      for(int nn = 0; nn < 4; nn++){
        acc[t][nn] = __builtin_amdgcn_mfma_f32_16x16x32_f16(apl[t], bfrag(2+kb2,  nn), acc[t][nn], 0,0,0);
        acc[t][nn] = __builtin_amdgcn_mfma_f32_16x16x32_f16(aam[t], bfrag(10+kb2, nn), acc[t][nn], 0,0,0);
        acc[t][nn] = __builtin_amdgcn_mfma_f32_16x16x32_f16(aat[t], bfrag(18+kb2, nn), acc[t][nn], 0,0,0);
      }
    }
  }

  #pragma unroll
  for(int t = 0; t < 2; t++){
    #pragma unroll
    for(int nn = 0; nn < 4; nn++){
      int n = c0 + nn*16 + mi;
      #pragma unroll
      for(int r = 0; r < 4; r++){
        int m = m0 + t*16 + q*4 + r;
        if(m < NN){
          float* cp = hB + (size_t)m*o + n;
          float base = init ? bias[n] : *cp;
          *cp = base + acc[t][nn][r];
        }
      }
    }
  }
}

// ---------------- ReLU + BatchNorm ----------------

__global__ __launch_bounds__(256) void k_bn_stats(const float* __restrict__ H, int dout,
                                                  float* __restrict__ colsum, float* __restrict__ colss){
  int tid = threadIdx.x;
  int gid = blockIdx.x*256 + tid;
  int stride = gridDim.x*256;
  int total = NN * dout;
  float s = 0.f, ss = 0.f;
  for(int i = gid; i < total; i += stride){
    float v = fmaxf(H[i], 0.f);
    s += v; ss += v*v;
  }
  __shared__ float shs[256], shss[256];
  shs[tid] = s; shss[tid] = ss;
  __syncthreads();
  if(tid < dout){
    float ts = 0.f, tss = 0.f;
    for(int i = tid; i < 256; i += dout){ ts += shs[i]; tss += shss[i]; }
    atomicAdd(&colsum[tid], ts);
    atomicAdd(&colss[tid], tss);
  }
}

__global__ void k_bn_apply(const float* __restrict__ H, int dout,
                           const float* __restrict__ colsum, const float* __restrict__ colss,
                           const float* __restrict__ gamma, const float* __restrict__ beta,
                           _Float16* __restrict__ out){
  int i = blockIdx.x*blockDim.x + threadIdx.x;
  int total = NN * dout;
  if(i >= total) return;
  int c = i & (dout - 1);
  float mean = colsum[c] / (float)NN;
  float var  = colss[c] / (float)NN - mean*mean;
  float inv  = rsqrtf(fmaxf(var, 0.f) + EPSV);
  float v = fmaxf(H[i], 0.f);
  out[i] = (_Float16)((v - mean) * inv * gamma[c] + beta[c]);
}

// ---------------- classifier ----------------

__global__ __launch_bounds__(256) void k_cls(const _Float16* __restrict__ h,
    const float* __restrict__ Wc, const float* __restrict__ bc,
    float* __restrict__ out){
  __shared__ float w[640];
  __shared__ float bb[16];
  int tid = threadIdx.x;
  for(int i = tid; i < 640; i += 256) w[i] = Wc[i];
  if(tid < 10) bb[tid] = bc[tid];
  __syncthreads();
  int idx = blockIdx.x*256 + tid;
  int n = idx >> 4;
  int c = idx & 15;
  if(n < NN && c < 10){
    float acc = bb[c];
    const _Float16* hp = h + (size_t)n*64;
    #pragma unroll
    for(int k = 0; k < 64; k++) acc += (float)hp[k] * w[k*10 + c];
    out[(size_t)n*10 + c] = acc;
  }
}

// ---------------- launch ----------------

extern "C" void kernel_launch(void* const* d_in, const int* in_sizes, int n_in,
                              void* d_out, int out_size, void* d_ws, size_t ws_size,
                              hipStream_t stream){
  const float* x = (const float*)d_in[0];
  const int* edge = (const int*)d_in[1];
  const int* esrc = edge;
  const int* edst = edge + NE;
  const float* W[4]  = {(const float*)d_in[2],  (const float*)d_in[6],
                        (const float*)d_in[10], (const float*)d_in[14]};
  const float* bb[4] = {(const float*)d_in[3],  (const float*)d_in[7],
                        (const float*)d_in[11], (const float*)d_in[15]};
  const float* gm[4] = {(const float*)d_in[4],  (const float*)d_in[8],
                        (const float*)d_in[12], (const float*)d_in[16]};
  const float* bt[4] = {(const float*)d_in[5],  (const float*)d_in[9],
                        (const float*)d_in[13], (const float*)d_in[17]};
  const float* Wc = (const float*)d_in[18];
  const float* bc = (const float*)d_in[19];
  (void)in_sizes; (void)n_in; (void)out_size; (void)ws_size;

  // workspace carve (~156 MB; proven-safe envelope)
  char* p = (char*)d_ws;
  auto alloc = [&](size_t bytes)->char*{
    char* r = p; p += (bytes + 255) & ~(size_t)255; return r;
  };
  _Float16* hA   = (_Float16*)alloc((size_t)NN*256*2);  // 25.6 MB
  float*    hB   = (float*)   alloc((size_t)NN*256*4);  // 51.2 MB
  _Float16* agg0 = (_Float16*)alloc((size_t)NN*256*2);  // 25.6 MB
  _Float16* agg1 = (_Float16*)alloc((size_t)NN*256*2);  // 25.6 MB
  int*   deg    = (int*)  alloc((size_t)NN*4);
  float* logdeg = (float*)alloc((size_t)NN*4);
  float* amp    = (float*)alloc((size_t)NN*4);
  float* att    = (float*)alloc((size_t)NN*4);
  int*   rowptr = (int*)  alloc((size_t)(NN+1)*4);
  int*   cursor = (int*)  alloc((size_t)NN*4);
  int*   colidx = (int*)  alloc((size_t)NE*4);
  int*   bsum   = (int*)  alloc((size_t)(NB+1)*4);
  float* colsum = (float*)alloc(256*4);
  float* colss  = (float*)alloc(256*4);
  float* dsum   = (float*)alloc(256);

  const int din[4]  = {64, 128, 256, 128};
  const int dto[4]  = {128, 256, 128, 64};
  _Float16* Wp[4][4];
  PackArgs pa; int pj = 0, poff = 0;
  for(int l = 0; l < 4; l++)
    for(int c = 0; c < din[l]/64; c++){
      Wp[l][c] = (_Float16*)alloc((size_t)832*dto[l]*2);
      pa.job[pj] = { W[l], Wp[l][c], din[l], dto[l], c*64, poff };
      poff += 832*dto[l]; pj++;
    }
  pa.total = poff;

  hipMemsetAsync(deg, 0, (size_t)NN*4, stream);
  hipMemsetAsync(dsum, 0, 4, stream);

  k_pack_all<<<(pa.total+255)/256, 256, 0, stream>>>(pa);
  k_deg     <<<(NE+255)/256, 256, 0, stream>>>(edst, deg);
  k_logdeg  <<<(NN+255)/256, 256, 0, stream>>>(deg, logdeg, dsum);
  k_scalers <<<(NN+255)/256, 256, 0, stream>>>(logdeg, dsum, amp, att);
  k_scan1   <<<NB, 1024, 0, stream>>>(deg, rowptr, bsum);
  k_scan2   <<<1, 64, 0, stream>>>(bsum);
  k_scan3   <<<(NN+256)/256, 256, 0, stream>>>(rowptr, cursor, bsum);
  k_fill    <<<(NE+255)/256, 256, 0, stream>>>(esrc, edst, cursor, colidx);
  k_cvtx    <<<(NN*64+255)/256, 256, 0, stream>>>(x, hA);

  for(int l = 0; l < 4; l++){
    int d = din[l], o = dto[l];
    int nch = d / 64;
    dim3 g(o/64, (NN+127)/128);
    for(int cp2 = 0; cp2 < nch; cp2 += 2){      // pass covers chunks cp2 (+cp2+1)
      int j0 = cp2*64;
      if(d == 64)
        k_agg2<<<(NN+7)/8, 256, 0, stream>>>(hA, d, j0, 1, rowptr, colidx, agg0, agg0);
      else
        k_agg2<<<(NN+3)/4, 256, 0, stream>>>(hA, d, j0, 0, rowptr, colidx, agg0, agg1);
      k_mfma<<<g, 256, 0, stream>>>(hA, d, j0, agg0, amp, att, Wp[l][cp2], o, bb[l], hB, cp2==0);
      if(cp2+1 < nch)
        k_mfma<<<g, 256, 0, stream>>>(hA, d, j0+64, agg1, amp, att, Wp[l][cp2+1], o, bb[l], hB, 0);
    }
    hipMemsetAsync(colsum, 0, (size_t)o*4, stream);
    hipMemsetAsync(colss,  0, (size_t)o*4, stream);
    k_bn_stats<<<256, 256, 0, stream>>>(hB, o, colsum, colss);
    k_bn_apply<<<(NN*o+255)/256, 256, 0, stream>>>(hB, o, colsum, colss, gm[l], bt[l], hA);
  }
  k_cls<<<(NN*16+255)/256, 256, 0, stream>>>(hA, Wc, bc, (float*)d_out);
}

// Round 8
// 862.112 us; speedup vs baseline: 1.6272x; 1.0665x over previous
//
#include <hip/hip_runtime.h>
#include <hip/hip_bf16.h>

#define NN 50000
#define NE 800000
#define EPSV 1e-5f
#define NB 49   // scan blocks: ceil(NN/1024)

typedef _Float16 h8 __attribute__((ext_vector_type(8)));
typedef _Float16 h2v __attribute__((ext_vector_type(2)));
typedef float    f4 __attribute__((ext_vector_type(4)));

// ---------------- graph preprocessing ----------------

__global__ void k_deg(const int* __restrict__ dst, int* __restrict__ deg){
  int e = blockIdx.x*blockDim.x + threadIdx.x;
  if(e < NE) atomicAdd(&deg[dst[e]], 1);
}

__global__ void k_logdeg(const int* __restrict__ deg, float* __restrict__ logdeg,
                         float* __restrict__ dsum){
  int i = blockIdx.x*blockDim.x + threadIdx.x;
  float v = 0.f;
  if(i < NN){ v = log1pf((float)deg[i]); logdeg[i] = v; }
  __shared__ float sh[256];
  sh[threadIdx.x] = v; __syncthreads();
  for(int off=128; off>0; off>>=1){
    if(threadIdx.x < off) sh[threadIdx.x] += sh[threadIdx.x+off];
    __syncthreads();
  }
  if(threadIdx.x == 0) atomicAdd(dsum, sh[0]);
}

__global__ void k_scalers(const float* __restrict__ logdeg, const float* __restrict__ dsum,
                          float* __restrict__ amp, float* __restrict__ att){
  int i = blockIdx.x*blockDim.x + threadIdx.x;
  if(i >= NN) return;
  float delta = dsum[0] / (float)NN;
  float ld = logdeg[i];
  amp[i] = ld / delta;
  att[i] = (ld > 0.f) ? (delta / fmaxf(ld, 1e-6f)) : 1.f;
}

// 3-phase parallel exclusive scan of deg -> rowptr (+cursor copy)
__global__ void k_scan1(const int* __restrict__ deg, int* __restrict__ rowptr,
                        int* __restrict__ bsum){
  __shared__ int buf[1024];
  int tid = threadIdx.x;
  int i = blockIdx.x*1024 + tid;
  int v = (i < NN) ? deg[i] : 0;
  buf[tid] = v; __syncthreads();
  for(int off=1; off<1024; off<<=1){
    int t = (tid >= off) ? buf[tid-off] : 0;
    __syncthreads();
    buf[tid] += t;
    __syncthreads();
  }
  if(i < NN) rowptr[i] = buf[tid] - v;
  if(tid == 1023) bsum[blockIdx.x] = buf[1023];
}

__global__ void k_scan2(int* __restrict__ bsum){
  if(threadIdx.x == 0){
    int s = 0;
    for(int b = 0; b < NB; b++){ int t = bsum[b]; bsum[b] = s; s += t; }
    bsum[NB] = s;
  }
}

__global__ void k_scan3(int* __restrict__ rowptr, int* __restrict__ cursor,
                        const int* __restrict__ bsum){
  int i = blockIdx.x*256 + threadIdx.x;
  if(i < NN){
    int v = rowptr[i] + bsum[i >> 10];
    rowptr[i] = v; cursor[i] = v;
  }
  if(i == NN) rowptr[NN] = bsum[NB];
}

__global__ void k_fill(const int* __restrict__ src, const int* __restrict__ dst,
                       int* __restrict__ cursor, int* __restrict__ colidx){
  int e = blockIdx.x*blockDim.x + threadIdx.x;
  if(e < NE){
    int pos = atomicAdd(&cursor[dst[e]], 1);
    colidx[pos] = src[e];
  }
}

__global__ void k_cvtx(const float* __restrict__ x, _Float16* __restrict__ hA){
  int i = blockIdx.x*256 + threadIdx.x;
  if(i < NN*64) hA[i] = (_Float16)x[i];
}

// ---------------- wide per-node aggregation ----------------
// Covers 128 feature columns (two 64-col chunks) per pass: lane handles 2
// adjacent cols via one 4-B load per edge; 4-way edge unroll for MLP.
// two==1 (d=64): 2 nodes per wave, 64-col chunk, all output to agg0.
// Chunk buffer layout: agg[n*256 + {0,64,128,192} + col] = mean|min|max|std.

__global__ __launch_bounds__(256) void k_agg2(
    const _Float16* __restrict__ h, int d, int j0, int two,
    const int* __restrict__ rowptr, const int* __restrict__ colidx,
    _Float16* __restrict__ agg0, _Float16* __restrict__ agg1)
{
  int wv = threadIdx.x >> 6, lane = threadIdx.x & 63;
  int n, c;
  if(two){ n = blockIdx.x*8 + wv*2 + (lane>>5); c = (lane&31)<<1; }
  else   { n = blockIdx.x*4 + wv;               c = lane<<1; }
  if(n >= NN) return;
  int beg = rowptr[n], end = rowptr[n+1];
  const _Float16* hp = h + j0 + c;
  float s0=0.f,s1=0.f,q0=0.f,q1=0.f;
  float mn0=INFINITY,mn1=INFINITY,mx0=-INFINITY,mx1=-INFINITY;

#define ACC2(v) { float a=(float)(v)[0], b=(float)(v)[1]; \
    s0+=a; q0+=a*a; mn0=fminf(mn0,a); mx0=fmaxf(mx0,a); \
    s1+=b; q1+=b*b; mn1=fminf(mn1,b); mx1=fmaxf(mx1,b); }

  int e = beg;
  for(; e+4 <= end; e+=4){
    int i0=colidx[e], i1=colidx[e+1], i2=colidx[e+2], i3=colidx[e+3];
    h2v v0 = *(const h2v*)(hp + (size_t)i0*d);
    h2v v1 = *(const h2v*)(hp + (size_t)i1*d);
    h2v v2 = *(const h2v*)(hp + (size_t)i2*d);
    h2v v3 = *(const h2v*)(hp + (size_t)i3*d);
    ACC2(v0) ACC2(v1) ACC2(v2) ACC2(v3)
  }
  for(; e < end; e++){
    h2v v = *(const h2v*)(hp + (size_t)colidx[e]*d);
    ACC2(v)
  }
#undef ACC2

  float cnt = (end>beg) ? (float)(end-beg) : 1.f;
  float mean0 = s0/cnt, mean1 = s1/cnt;
  float sd0 = sqrtf(fmaxf(q0/cnt - mean0*mean0, 0.f) + EPSV);
  float sd1 = sqrtf(fmaxf(q1/cnt - mean1*mean1, 0.f) + EPSV);
  if(end <= beg){ mn0=0.f; mn1=0.f; mx0=0.f; mx1=0.f; }

  _Float16* dst; int cl;
  if(c < 64){ dst = agg0; cl = c; } else { dst = agg1; cl = c-64; }
  size_t base = (size_t)n*256 + cl;
  h2v o0 = {(_Float16)mean0,(_Float16)mean1};
  h2v o1 = {(_Float16)mn0,(_Float16)mn1};
  h2v o2 = {(_Float16)mx0,(_Float16)mx1};
  h2v o3 = {(_Float16)sd0,(_Float16)sd1};
  *(h2v*)(dst+base)       = o0;
  *(h2v*)(dst+base+64)    = o1;
  *(h2v*)(dst+base+128)   = o2;
  *(h2v*)(dst+base+192)   = o3;
}

// ---------------- fused W pre-pack (all layers/chunks, one kernel) ----------------
// Per chunk slab (contiguous 832*o halves): Wp[kb=K/32][nt=o/16][lane=64][j=8],
// k=kb*32+(lane>>4)*8+j, n=nt*16+(lane&15); row perm: k<64 -> j0+k ;
// [64,320)->(1+q)d+j0+r ; [320,576)->(5+q)d+j0+r ; [576,832)->(9+q)d+j0+r

struct PackJob { const float* W; _Float16* dst; int d, o, j0, start; };
struct PackArgs { PackJob job[9]; int total; };

__global__ void k_pack_all(PackArgs a){
  int idx = blockIdx.x*256 + threadIdx.x;
  if(idx >= a.total) return;
  int ji = 0;
  while(ji < 8 && idx >= a.job[ji+1].start) ji++;
  PackJob J = a.job[ji];
  int rel = idx - J.start;
  int j    = rel & 7;
  int lane = (rel >> 3) & 63;
  int rem  = rel >> 9;
  int ntiles = J.o >> 4;
  int kb = rem / ntiles;
  int nt = rem - kb*ntiles;
  int k = kb*32 + (lane>>4)*8 + j;
  int n = nt*16 + (lane&15);
  int srcrow;
  if(k < 64)       srcrow = J.j0 + k;
  else if(k < 320){ int t=k-64;  srcrow = (1+(t>>6))*J.d + J.j0 + (t&63); }
  else if(k < 576){ int t=k-320; srcrow = (5+(t>>6))*J.d + J.j0 + (t&63); }
  else            { int t=k-576; srcrow = (9+(t>>6))*J.d + J.j0 + (t&63); }
  J.dst[rel] = (_Float16)J.W[(size_t)srcrow*J.o + n];
}

// ---------------- fused MFMA layer GEMM ----------------
// One dispatch per layer: loops over nch 64-col chunks, accumulating the full
// 13d K-dim in registers. Epilogue: +bias, ReLU, fp16 store (no RMW).
// virtualA(chunk c) = [ hA[:,c64..] | aggs_c | amp*aggs_c | att*aggs_c ]

__global__ __launch_bounds__(256) void k_mfma_fused(
    const _Float16* __restrict__ hA, int d, int nch,
    const _Float16* __restrict__ aggs,          // [nch][NN][256]
    const float* __restrict__ amp, const float* __restrict__ att,
    const _Float16* __restrict__ Wp, int o,     // [nch][832*o]
    const float* __restrict__ bias,
    _Float16* __restrict__ out)                 // [NN][o], relu'd
{
  int tid  = threadIdx.x;
  int w    = tid >> 6;
  int lane = tid & 63;
  int mi   = lane & 15;
  int q    = lane >> 4;
  int m0   = blockIdx.y * 128 + w * 32;
  int c0   = blockIdx.x * 64;
  int ntiles = o >> 4;
  int nt0  = blockIdx.x * 4;

  int mrow[2];
  mrow[0] = min(m0 + mi,      NN-1);
  mrow[1] = min(m0 + 16 + mi, NN-1);
  _Float16 am16[2] = { (_Float16)amp[mrow[0]], (_Float16)amp[mrow[1]] };
  _Float16 at16[2] = { (_Float16)att[mrow[0]], (_Float16)att[mrow[1]] };

  f4 acc[2][4] = {};

  for(int c = 0; c < nch; c++){
    const _Float16* Wpc = Wp + (size_t)c*832*o;
    const _Float16* hAp[2];
    const _Float16* agp[2];
    hAp[0] = hA + (size_t)mrow[0]*d + c*64 + q*8;
    hAp[1] = hA + (size_t)mrow[1]*d + c*64 + q*8;
    agp[0] = aggs + (size_t)c*NN*256 + (size_t)mrow[0]*256 + q*8;
    agp[1] = aggs + (size_t)c*NN*256 + (size_t)mrow[1]*256 + q*8;

    auto bfrag = [&](int kb, int nn) -> h8 {
      return *(const h8*)(Wpc + (((size_t)kb*ntiles + nt0 + nn)*64 + lane)*8);
    };

    // ---- phase X: hA chunk, kb = 0,1 ----
    #pragma unroll
    for(int kb = 0; kb < 2; kb++){
      h8 a[2];
      #pragma unroll
      for(int t = 0; t < 2; t++) a[t] = *(const h8*)(hAp[t] + kb*32);
      #pragma unroll
      for(int t = 0; t < 2; t++)
        #pragma unroll
        for(int nn = 0; nn < 4; nn++)
          acc[t][nn] = __builtin_amdgcn_mfma_f32_16x16x32_f16(a[t], bfrag(kb,nn), acc[t][nn], 0,0,0);
    }

    // ---- aggs phases: one load, three packed-scale variants ----
    #pragma unroll 2
    for(int kb2 = 0; kb2 < 8; kb2++){
      h8 apl[2], aam[2], aat[2];
      #pragma unroll
      for(int t = 0; t < 2; t++){
        apl[t] = *(const h8*)(agp[t] + kb2*32);
        aam[t] = apl[t] * am16[t];
        aat[t] = apl[t] * at16[t];
      }
      #pragma unroll
      for(int t = 0; t < 2; t++){
        #pragma unroll
        for(int nn = 0; nn < 4; nn++){
          acc[t][nn] = __builtin_amdgcn_mfma_f32_16x16x32_f16(apl[t], bfrag(2+kb2,  nn), acc[t][nn], 0,0,0);
          acc[t][nn] = __builtin_amdgcn_mfma_f32_16x16x32_f16(aam[t], bfrag(10+kb2, nn), acc[t][nn], 0,0,0);
          acc[t][nn] = __builtin_amdgcn_mfma_f32_16x16x32_f16(aat[t], bfrag(18+kb2, nn), acc[t][nn], 0,0,0);
        }
      }
    }
  }

  // ---- epilogue: +bias, ReLU, fp16 store. D col = lane&15, row = q*4+reg ----
  #pragma unroll
  for(int t = 0; t < 2; t++){
    #pragma unroll
    for(int nn = 0; nn < 4; nn++){
      int n = c0 + nn*16 + mi;
      float bv = bias[n];
      #pragma unroll
      for(int r = 0; r < 4; r++){
        int m = m0 + t*16 + q*4 + r;
        if(m < NN)
          out[(size_t)m*o + n] = (_Float16)fmaxf(bv + acc[t][nn][r], 0.f);
      }
    }
  }
}

// ---------------- BatchNorm (input already relu'd, fp16) ----------------

__global__ __launch_bounds__(256) void k_bn_stats(const _Float16* __restrict__ H, int dout,
                                                  float* __restrict__ colsum, float* __restrict__ colss){
  int tid = threadIdx.x;
  int gid = blockIdx.x*256 + tid;
  int stride = gridDim.x*256;
  int total = NN * dout;
  float s = 0.f, ss = 0.f;
  for(int i = gid; i < total; i += stride){
    float v = (float)H[i];
    s += v; ss += v*v;
  }
  __shared__ float shs[256], shss[256];
  shs[tid] = s; shss[tid] = ss;
  __syncthreads();
  if(tid < dout){
    float ts = 0.f, tss = 0.f;
    for(int i = tid; i < 256; i += dout){ ts += shs[i]; tss += shss[i]; }
    atomicAdd(&colsum[tid], ts);
    atomicAdd(&colss[tid], tss);
  }
}

__global__ void k_bn_apply(const _Float16* __restrict__ H, int dout,
                           const float* __restrict__ colsum, const float* __restrict__ colss,
                           const float* __restrict__ gamma, const float* __restrict__ beta,
                           _Float16* __restrict__ out){
  int i = blockIdx.x*blockDim.x + threadIdx.x;
  int total = NN * dout;
  if(i >= total) return;
  int c = i & (dout - 1);
  float mean = colsum[c] / (float)NN;
  float var  = colss[c] / (float)NN - mean*mean;
  float inv  = rsqrtf(fmaxf(var, 0.f) + EPSV);
  float v = (float)H[i];
  out[i] = (_Float16)((v - mean) * inv * gamma[c] + beta[c]);
}

// ---------------- classifier ----------------

__global__ __launch_bounds__(256) void k_cls(const _Float16* __restrict__ h,
    const float* __restrict__ Wc, const float* __restrict__ bc,
    float* __restrict__ out){
  __shared__ float w[640];
  __shared__ float bb[16];
  int tid = threadIdx.x;
  for(int i = tid; i < 640; i += 256) w[i] = Wc[i];
  if(tid < 10) bb[tid] = bc[tid];
  __syncthreads();
  int idx = blockIdx.x*256 + tid;
  int n = idx >> 4;
  int c = idx & 15;
  if(n < NN && c < 10){
    float acc = bb[c];
    const _Float16* hp = h + (size_t)n*64;
    #pragma unroll
    for(int k = 0; k < 64; k++) acc += (float)hp[k] * w[k*10 + c];
    out[(size_t)n*10 + c] = acc;
  }
}

// ---------------- launch ----------------

extern "C" void kernel_launch(void* const* d_in, const int* in_sizes, int n_in,
                              void* d_out, int out_size, void* d_ws, size_t ws_size,
                              hipStream_t stream){
  const float* x = (const float*)d_in[0];
  const int* edge = (const int*)d_in[1];
  const int* esrc = edge;
  const int* edst = edge + NE;
  const float* W[4]  = {(const float*)d_in[2],  (const float*)d_in[6],
                        (const float*)d_in[10], (const float*)d_in[14]};
  const float* bb[4] = {(const float*)d_in[3],  (const float*)d_in[7],
                        (const float*)d_in[11], (const float*)d_in[15]};
  const float* gm[4] = {(const float*)d_in[4],  (const float*)d_in[8],
                        (const float*)d_in[12], (const float*)d_in[16]};
  const float* bt[4] = {(const float*)d_in[5],  (const float*)d_in[9],
                        (const float*)d_in[13], (const float*)d_in[17]};
  const float* Wc = (const float*)d_in[18];
  const float* bc = (const float*)d_in[19];
  (void)in_sizes; (void)n_in; (void)out_size; (void)ws_size;

  // workspace carve (~158 MB; proven-safe envelope)
  char* p = (char*)d_ws;
  auto alloc = [&](size_t bytes)->char*{
    char* r = p; p += (bytes + 255) & ~(size_t)255; return r;
  };
  _Float16* hA   = (_Float16*)alloc((size_t)NN*256*2);   // 25.6 MB
  _Float16* hB   = (_Float16*)alloc((size_t)NN*256*2);   // 25.6 MB (relu'd, fp16)
  _Float16* aggs = (_Float16*)alloc((size_t)4*NN*256*2); // 102.4 MB: [chunk][N][256]
  int*   deg    = (int*)  alloc((size_t)NN*4);
  float* logdeg = (float*)alloc((size_t)NN*4);
  float* amp    = (float*)alloc((size_t)NN*4);
  float* att    = (float*)alloc((size_t)NN*4);
  int*   rowptr = (int*)  alloc((size_t)(NN+1)*4);
  int*   cursor = (int*)  alloc((size_t)NN*4);
  int*   colidx = (int*)  alloc((size_t)NE*4);
  int*   bsum   = (int*)  alloc((size_t)(NB+1)*4);
  float* colsum = (float*)alloc(256*4);
  float* colss  = (float*)alloc(256*4);
  float* dsum   = (float*)alloc(256);

  const int din[4]  = {64, 128, 256, 128};
  const int dto[4]  = {128, 256, 128, 64};
  const size_t aggN = (size_t)NN*256;      // halves per chunk slab
  _Float16* WpL[4];
  PackArgs pa; int pj = 0, poff = 0;
  for(int l = 0; l < 4; l++){
    int nch = din[l]/64;
    WpL[l] = (_Float16*)alloc((size_t)nch*832*dto[l]*2);
    for(int c = 0; c < nch; c++){
      pa.job[pj] = { W[l], WpL[l] + (size_t)c*832*dto[l], din[l], dto[l], c*64, poff };
      poff += 832*dto[l]; pj++;
    }
  }
  pa.total = poff;

  hipMemsetAsync(deg, 0, (size_t)NN*4, stream);
  hipMemsetAsync(dsum, 0, 4, stream);

  k_pack_all<<<(pa.total+255)/256, 256, 0, stream>>>(pa);
  k_deg     <<<(NE+255)/256, 256, 0, stream>>>(edst, deg);
  k_logdeg  <<<(NN+255)/256, 256, 0, stream>>>(deg, logdeg, dsum);
  k_scalers <<<(NN+255)/256, 256, 0, stream>>>(logdeg, dsum, amp, att);
  k_scan1   <<<NB, 1024, 0, stream>>>(deg, rowptr, bsum);
  k_scan2   <<<1, 64, 0, stream>>>(bsum);
  k_scan3   <<<(NN+256)/256, 256, 0, stream>>>(rowptr, cursor, bsum);
  k_fill    <<<(NE+255)/256, 256, 0, stream>>>(esrc, edst, cursor, colidx);
  k_cvtx    <<<(NN*64+255)/256, 256, 0, stream>>>(x, hA);

  for(int l = 0; l < 4; l++){
    int d = din[l], o = dto[l];
    int nch = d / 64;
    // aggregation: 128 cols per pass into chunk slabs of the big aggs buffer
    for(int cp2 = 0; cp2 < nch; cp2 += 2){
      int j0 = cp2*64;
      if(d == 64)
        k_agg2<<<(NN+7)/8, 256, 0, stream>>>(hA, d, j0, 1, rowptr, colidx,
                                             aggs, aggs);
      else
        k_agg2<<<(NN+3)/4, 256, 0, stream>>>(hA, d, j0, 0, rowptr, colidx,
                                             aggs + (size_t)cp2*aggN,
                                             aggs + (size_t)(cp2+1)*aggN);
    }
    // one fused GEMM dispatch for the whole layer
    dim3 g(o/64, (NN+127)/128);
    k_mfma_fused<<<g, 256, 0, stream>>>(hA, d, nch, aggs, amp, att, WpL[l], o, bb[l], hB);
    hipMemsetAsync(colsum, 0, (size_t)o*4, stream);
    hipMemsetAsync(colss,  0, (size_t)o*4, stream);
    k_bn_stats<<<256, 256, 0, stream>>>(hB, o, colsum, colss);
    k_bn_apply<<<(NN*o+255)/256, 256, 0, stream>>>(hB, o, colsum, colss, gm[l], bt[l], hA);
  }
  k_cls<<<(NN*16+255)/256, 256, 0, stream>>>(hA, Wc, bc, (float*)d_out);
}

// Round 9
// 816.539 us; speedup vs baseline: 1.7180x; 1.0558x over previous
//
#include <hip/hip_runtime.h>
#include <hip/hip_bf16.h>

#define NN 50000
#define NE 800000
#define EPSV 1e-5f
#define NB 49   // scan blocks: ceil(NN/1024)

typedef _Float16 h8 __attribute__((ext_vector_type(8)));
typedef _Float16 h4 __attribute__((ext_vector_type(4)));
typedef _Float16 h2v __attribute__((ext_vector_type(2)));
typedef float    f4 __attribute__((ext_vector_type(4)));

// ---------------- graph preprocessing ----------------

__global__ void k_deg(const int* __restrict__ dst, int* __restrict__ deg){
  int e = blockIdx.x*blockDim.x + threadIdx.x;
  if(e < NE) atomicAdd(&deg[dst[e]], 1);
}

__global__ void k_logdeg(const int* __restrict__ deg, float* __restrict__ logdeg,
                         float* __restrict__ dsum){
  int i = blockIdx.x*blockDim.x + threadIdx.x;
  float v = 0.f;
  if(i < NN){ v = log1pf((float)deg[i]); logdeg[i] = v; }
  __shared__ float sh[256];
  sh[threadIdx.x] = v; __syncthreads();
  for(int off=128; off>0; off>>=1){
    if(threadIdx.x < off) sh[threadIdx.x] += sh[threadIdx.x+off];
    __syncthreads();
  }
  if(threadIdx.x == 0) atomicAdd(dsum, sh[0]);
}

__global__ void k_scalers(const float* __restrict__ logdeg, const float* __restrict__ dsum,
                          float* __restrict__ amp, float* __restrict__ att){
  int i = blockIdx.x*blockDim.x + threadIdx.x;
  if(i >= NN) return;
  float delta = dsum[0] / (float)NN;
  float ld = logdeg[i];
  amp[i] = ld / delta;
  att[i] = (ld > 0.f) ? (delta / fmaxf(ld, 1e-6f)) : 1.f;
}

// 3-phase parallel exclusive scan of deg -> rowptr (+cursor copy)
__global__ void k_scan1(const int* __restrict__ deg, int* __restrict__ rowptr,
                        int* __restrict__ bsum){
  __shared__ int buf[1024];
  int tid = threadIdx.x;
  int i = blockIdx.x*1024 + tid;
  int v = (i < NN) ? deg[i] : 0;
  buf[tid] = v; __syncthreads();
  for(int off=1; off<1024; off<<=1){
    int t = (tid >= off) ? buf[tid-off] : 0;
    __syncthreads();
    buf[tid] += t;
    __syncthreads();
  }
  if(i < NN) rowptr[i] = buf[tid] - v;
  if(tid == 1023) bsum[blockIdx.x] = buf[1023];
}

__global__ void k_scan2(int* __restrict__ bsum){
  if(threadIdx.x == 0){
    int s = 0;
    for(int b = 0; b < NB; b++){ int t = bsum[b]; bsum[b] = s; s += t; }
    bsum[NB] = s;
  }
}

__global__ void k_scan3(int* __restrict__ rowptr, int* __restrict__ cursor,
                        const int* __restrict__ bsum){
  int i = blockIdx.x*256 + threadIdx.x;
  if(i < NN){
    int v = rowptr[i] + bsum[i >> 10];
    rowptr[i] = v; cursor[i] = v;
  }
  if(i == NN) rowptr[NN] = bsum[NB];
}

__global__ void k_fill(const int* __restrict__ src, const int* __restrict__ dst,
                       int* __restrict__ cursor, int* __restrict__ colidx){
  int e = blockIdx.x*blockDim.x + threadIdx.x;
  if(e < NE){
    int pos = atomicAdd(&cursor[dst[e]], 1);
    colidx[pos] = src[e];
  }
}

__global__ void k_cvtx(const float* __restrict__ x, _Float16* __restrict__ hA){
  int i = blockIdx.x*256 + threadIdx.x;
  if(i < NN*64) hA[i] = (_Float16)x[i];
}

// ---------------- one-pass per-node aggregation (4 cols/lane, 8 B loads) ----------------
// One dispatch per layer: a wave covers min(d,256) columns; lanes-per-node =
// d/4, nodes-per-wave = 64/lpn. Writes all chunk slabs of aggs:
// aggs[chunk][n*256 + {0,64,128,192} + cl] = mean|min|max|std.

__global__ __launch_bounds__(256) void k_agg4(
    const _Float16* __restrict__ h, int d,
    const int* __restrict__ rowptr, const int* __restrict__ colidx,
    _Float16* __restrict__ aggs, size_t aggN)
{
  int wv = threadIdx.x >> 6, lane = threadIdx.x & 63;
  int lpn = d >> 2;                 // lanes per node: 16/32/64
  int npw = 64 / lpn;               // nodes per wave: 4/2/1
  int n = blockIdx.x*(npw*4) + wv*npw + (lane / lpn);
  int c = (lane % lpn) * 4;         // 4 adjacent feature cols
  if(n >= NN) return;
  int beg = rowptr[n], end = rowptr[n+1];
  const _Float16* hp = h + c;

  float s0=0,s1=0,s2=0,s3=0, q0=0,q1=0,q2=0,q3=0;
  float mn0=INFINITY,mn1=INFINITY,mn2=INFINITY,mn3=INFINITY;
  float mx0=-INFINITY,mx1=-INFINITY,mx2=-INFINITY,mx3=-INFINITY;

#define ACC4(v) { float a0=(float)(v)[0],a1=(float)(v)[1],a2=(float)(v)[2],a3=(float)(v)[3]; \
    s0+=a0; q0+=a0*a0; mn0=fminf(mn0,a0); mx0=fmaxf(mx0,a0); \
    s1+=a1; q1+=a1*a1; mn1=fminf(mn1,a1); mx1=fmaxf(mx1,a1); \
    s2+=a2; q2+=a2*a2; mn2=fminf(mn2,a2); mx2=fmaxf(mx2,a2); \
    s3+=a3; q3+=a3*a3; mn3=fminf(mn3,a3); mx3=fmaxf(mx3,a3); }

  int e = beg;
  for(; e+4 <= end; e+=4){
    int i0=colidx[e], i1=colidx[e+1], i2=colidx[e+2], i3=colidx[e+3];
    h4 v0 = *(const h4*)(hp + (size_t)i0*d);
    h4 v1 = *(const h4*)(hp + (size_t)i1*d);
    h4 v2 = *(const h4*)(hp + (size_t)i2*d);
    h4 v3 = *(const h4*)(hp + (size_t)i3*d);
    ACC4(v0) ACC4(v1) ACC4(v2) ACC4(v3)
  }
  for(; e < end; e++){
    h4 v = *(const h4*)(hp + (size_t)colidx[e]*d);
    ACC4(v)
  }
#undef ACC4

  float cnt = (end>beg) ? (float)(end-beg) : 1.f;
  float me0=s0/cnt, me1=s1/cnt, me2=s2/cnt, me3=s3/cnt;
  float sd0 = sqrtf(fmaxf(q0/cnt - me0*me0, 0.f) + EPSV);
  float sd1 = sqrtf(fmaxf(q1/cnt - me1*me1, 0.f) + EPSV);
  float sd2 = sqrtf(fmaxf(q2/cnt - me2*me2, 0.f) + EPSV);
  float sd3 = sqrtf(fmaxf(q3/cnt - me3*me3, 0.f) + EPSV);
  if(end <= beg){ mn0=mn1=mn2=mn3=0.f; mx0=mx1=mx2=mx3=0.f; }

  _Float16* dst = aggs + (size_t)(c>>6)*aggN + (size_t)n*256 + (c & 63);
  h4 om = {(_Float16)me0,(_Float16)me1,(_Float16)me2,(_Float16)me3};
  h4 on = {(_Float16)mn0,(_Float16)mn1,(_Float16)mn2,(_Float16)mn3};
  h4 ox = {(_Float16)mx0,(_Float16)mx1,(_Float16)mx2,(_Float16)mx3};
  h4 os = {(_Float16)sd0,(_Float16)sd1,(_Float16)sd2,(_Float16)sd3};
  *(h4*)(dst)       = om;
  *(h4*)(dst + 64)  = on;
  *(h4*)(dst + 128) = ox;
  *(h4*)(dst + 192) = os;
}

// ---------------- fused W pre-pack (all layers/chunks, one kernel) ----------------
// Per chunk slab (contiguous 832*o halves): Wp[kb=K/32][nt=o/16][lane=64][j=8],
// k=kb*32+(lane>>4)*8+j, n=nt*16+(lane&15); row perm: k<64 -> j0+k ;
// [64,320)->(1+q)d+j0+r ; [320,576)->(5+q)d+j0+r ; [576,832)->(9+q)d+j0+r

struct PackJob { const float* W; _Float16* dst; int d, o, j0, start; };
struct PackArgs { PackJob job[9]; int total; };

__global__ void k_pack_all(PackArgs a){
  int idx = blockIdx.x*256 + threadIdx.x;
  if(idx >= a.total) return;
  int ji = 0;
  while(ji < 8 && idx >= a.job[ji+1].start) ji++;
  PackJob J = a.job[ji];
  int rel = idx - J.start;
  int j    = rel & 7;
  int lane = (rel >> 3) & 63;
  int rem  = rel >> 9;
  int ntiles = J.o >> 4;
  int kb = rem / ntiles;
  int nt = rem - kb*ntiles;
  int k = kb*32 + (lane>>4)*8 + j;
  int n = nt*16 + (lane&15);
  int srcrow;
  if(k < 64)       srcrow = J.j0 + k;
  else if(k < 320){ int t=k-64;  srcrow = (1+(t>>6))*J.d + J.j0 + (t&63); }
  else if(k < 576){ int t=k-320; srcrow = (5+(t>>6))*J.d + J.j0 + (t&63); }
  else            { int t=k-576; srcrow = (9+(t>>6))*J.d + J.j0 + (t&63); }
  J.dst[rel] = (_Float16)J.W[(size_t)srcrow*J.o + n];
}

// ---------------- fused MFMA layer GEMM ----------------
// One dispatch per layer; K accumulated in registers across chunks.
// Per chunk: ALL 18 A-fragment loads issued up-front (MLP), then 96 MFMAs.
// Epilogue: +bias, ReLU, fp16 store.

__global__ __launch_bounds__(256) void k_mfma_fused(
    const _Float16* __restrict__ hA, int d, int nch,
    const _Float16* __restrict__ aggs,          // [nch][NN][256]
    const float* __restrict__ amp, const float* __restrict__ att,
    const _Float16* __restrict__ Wp, int o,     // [nch][832*o]
    const float* __restrict__ bias,
    _Float16* __restrict__ out)                 // [NN][o], relu'd
{
  int tid  = threadIdx.x;
  int w    = tid >> 6;
  int lane = tid & 63;
  int mi   = lane & 15;
  int q    = lane >> 4;
  int m0   = blockIdx.y * 128 + w * 32;
  int c0   = blockIdx.x * 64;
  int ntiles = o >> 4;
  int nt0  = blockIdx.x * 4;

  int mrow[2];
  mrow[0] = min(m0 + mi,      NN-1);
  mrow[1] = min(m0 + 16 + mi, NN-1);
  _Float16 am16[2] = { (_Float16)amp[mrow[0]], (_Float16)amp[mrow[1]] };
  _Float16 at16[2] = { (_Float16)att[mrow[0]], (_Float16)att[mrow[1]] };
  const _Float16* hAb[2];
  const _Float16* agb[2];
  hAb[0] = hA + (size_t)mrow[0]*d + q*8;
  hAb[1] = hA + (size_t)mrow[1]*d + q*8;
  agb[0] = aggs + (size_t)mrow[0]*256 + q*8;
  agb[1] = aggs + (size_t)mrow[1]*256 + q*8;

  f4 acc[2][4] = {};
  const size_t aggN = (size_t)NN*256;

  for(int c = 0; c < nch; c++){
    const _Float16* Wpc = Wp + (size_t)c*832*o;
    auto bfrag = [&](int kb, int nn) -> h8 {
      return *(const h8*)(Wpc + (((size_t)kb*ntiles + nt0 + nn)*64 + lane)*8);
    };

    // ---- issue ALL A loads for this chunk up-front ----
    h8 ax[2][2];     // [kb][t]   hA fragment
    h8 ag[8][2];     // [kb2][t]  aggs fragment
    #pragma unroll
    for(int kb = 0; kb < 2; kb++)
      #pragma unroll
      for(int t = 0; t < 2; t++)
        ax[kb][t] = *(const h8*)(hAb[t] + c*64 + kb*32);
    #pragma unroll
    for(int kb2 = 0; kb2 < 8; kb2++)
      #pragma unroll
      for(int t = 0; t < 2; t++)
        ag[kb2][t] = *(const h8*)(agb[t] + (size_t)c*aggN + kb2*32);

    // ---- phase X: hA chunk, kb = 0,1 ----
    #pragma unroll
    for(int kb = 0; kb < 2; kb++)
      #pragma unroll
      for(int t = 0; t < 2; t++)
        #pragma unroll
        for(int nn = 0; nn < 4; nn++)
          acc[t][nn] = __builtin_amdgcn_mfma_f32_16x16x32_f16(ax[kb][t], bfrag(kb,nn), acc[t][nn], 0,0,0);

    // ---- aggs phases: plain / amp-scaled / att-scaled ----
    #pragma unroll
    for(int kb2 = 0; kb2 < 8; kb2++){
      #pragma unroll
      for(int t = 0; t < 2; t++){
        h8 apl = ag[kb2][t];
        h8 aam = apl * am16[t];
        h8 aat = apl * at16[t];
        #pragma unroll
        for(int nn = 0; nn < 4; nn++){
          acc[t][nn] = __builtin_amdgcn_mfma_f32_16x16x32_f16(apl, bfrag(2+kb2,  nn), acc[t][nn], 0,0,0);
          acc[t][nn] = __builtin_amdgcn_mfma_f32_16x16x32_f16(aam, bfrag(10+kb2, nn), acc[t][nn], 0,0,0);
          acc[t][nn] = __builtin_amdgcn_mfma_f32_16x16x32_f16(aat, bfrag(18+kb2, nn), acc[t][nn], 0,0,0);
        }
      }
    }
  }

  // ---- epilogue: +bias, ReLU, fp16 store. D col = lane&15, row = q*4+reg ----
  #pragma unroll
  for(int t = 0; t < 2; t++){
    #pragma unroll
    for(int nn = 0; nn < 4; nn++){
      int n = c0 + nn*16 + mi;
      float bv = bias[n];
      #pragma unroll
      for(int r = 0; r < 4; r++){
        int m = m0 + t*16 + q*4 + r;
        if(m < NN)
          out[(size_t)m*o + n] = (_Float16)fmaxf(bv + acc[t][nn][r], 0.f);
      }
    }
  }
}

// ---------------- BatchNorm (input already relu'd, fp16) ----------------

__global__ __launch_bounds__(256) void k_bn_stats(const _Float16* __restrict__ H, int dout,
                                                  float* __restrict__ colsum, float* __restrict__ colss){
  int tid = threadIdx.x;
  int gid = blockIdx.x*256 + tid;
  int stride = gridDim.x*256;
  int total = NN * dout;
  float s = 0.f, ss = 0.f;
  for(int i = gid; i < total; i += stride){
    float v = (float)H[i];
    s += v; ss += v*v;
  }
  __shared__ float shs[256], shss[256];
  shs[tid] = s; shss[tid] = ss;
  __syncthreads();
  if(tid < dout){
    float ts = 0.f, tss = 0.f;
    for(int i = tid; i < 256; i += dout){ ts += shs[i]; tss += shss[i]; }
    atomicAdd(&colsum[tid], ts);
    atomicAdd(&colss[tid], tss);
  }
}

__global__ void k_bn_apply(const _Float16* __restrict__ H, int dout,
                           const float* __restrict__ colsum, const float* __restrict__ colss,
                           const float* __restrict__ gamma, const float* __restrict__ beta,
                           _Float16* __restrict__ out){
  int i = blockIdx.x*blockDim.x + threadIdx.x;
  int total = NN * dout;
  if(i >= total) return;
  int c = i & (dout - 1);
  float mean = colsum[c] / (float)NN;
  float var  = colss[c] / (float)NN - mean*mean;
  float inv  = rsqrtf(fmaxf(var, 0.f) + EPSV);
  float v = (float)H[i];
  out[i] = (_Float16)((v - mean) * inv * gamma[c] + beta[c]);
}

// ---------------- classifier ----------------

__global__ __launch_bounds__(256) void k_cls(const _Float16* __restrict__ h,
    const float* __restrict__ Wc, const float* __restrict__ bc,
    float* __restrict__ out){
  __shared__ float w[640];
  __shared__ float bb[16];
  int tid = threadIdx.x;
  for(int i = tid; i < 640; i += 256) w[i] = Wc[i];
  if(tid < 10) bb[tid] = bc[tid];
  __syncthreads();
  int idx = blockIdx.x*256 + tid;
  int n = idx >> 4;
  int c = idx & 15;
  if(n < NN && c < 10){
    float acc = bb[c];
    const _Float16* hp = h + (size_t)n*64;
    #pragma unroll
    for(int k = 0; k < 64; k++) acc += (float)hp[k] * w[k*10 + c];
    out[(size_t)n*10 + c] = acc;
  }
}

// ---------------- launch ----------------

extern "C" void kernel_launch(void* const* d_in, const int* in_sizes, int n_in,
                              void* d_out, int out_size, void* d_ws, size_t ws_size,
                              hipStream_t stream){
  const float* x = (const float*)d_in[0];
  const int* edge = (const int*)d_in[1];
  const int* esrc = edge;
  const int* edst = edge + NE;
  const float* W[4]  = {(const float*)d_in[2],  (const float*)d_in[6],
                        (const float*)d_in[10], (const float*)d_in[14]};
  const float* bb[4] = {(const float*)d_in[3],  (const float*)d_in[7],
                        (const float*)d_in[11], (const float*)d_in[15]};
  const float* gm[4] = {(const float*)d_in[4],  (const float*)d_in[8],
                        (const float*)d_in[12], (const float*)d_in[16]};
  const float* bt[4] = {(const float*)d_in[5],  (const float*)d_in[9],
                        (const float*)d_in[13], (const float*)d_in[17]};
  const float* Wc = (const float*)d_in[18];
  const float* bc = (const float*)d_in[19];
  (void)in_sizes; (void)n_in; (void)out_size; (void)ws_size;

  // workspace carve (~158 MB; proven-safe envelope)
  char* p = (char*)d_ws;
  auto alloc = [&](size_t bytes)->char*{
    char* r = p; p += (bytes + 255) & ~(size_t)255; return r;
  };
  _Float16* hA   = (_Float16*)alloc((size_t)NN*256*2);   // 25.6 MB
  _Float16* hB   = (_Float16*)alloc((size_t)NN*256*2);   // 25.6 MB (relu'd, fp16)
  _Float16* aggs = (_Float16*)alloc((size_t)4*NN*256*2); // 102.4 MB: [chunk][N][256]
  int*   deg    = (int*)  alloc((size_t)NN*4);
  float* logdeg = (float*)alloc((size_t)NN*4);
  float* amp    = (float*)alloc((size_t)NN*4);
  float* att    = (float*)alloc((size_t)NN*4);
  int*   rowptr = (int*)  alloc((size_t)(NN+1)*4);
  int*   cursor = (int*)  alloc((size_t)NN*4);
  int*   colidx = (int*)  alloc((size_t)NE*4);
  int*   bsum   = (int*)  alloc((size_t)(NB+1)*4);
  float* colsumL= (float*)alloc(4*256*4);   // per-layer BN partials
  float* colssL = (float*)alloc(4*256*4);
  float* dsum   = (float*)alloc(256);

  const int din[4]  = {64, 128, 256, 128};
  const int dto[4]  = {128, 256, 128, 64};
  const size_t aggN = (size_t)NN*256;      // halves per chunk slab
  _Float16* WpL[4];
  PackArgs pa; int pj = 0, poff = 0;
  for(int l = 0; l < 4; l++){
    int nch = din[l]/64;
    WpL[l] = (_Float16*)alloc((size_t)nch*832*dto[l]*2);
    for(int c = 0; c < nch; c++){
      pa.job[pj] = { W[l], WpL[l] + (size_t)c*832*dto[l], din[l], dto[l], c*64, poff };
      poff += 832*dto[l]; pj++;
    }
  }
  pa.total = poff;

  hipMemsetAsync(deg, 0, (size_t)NN*4, stream);
  hipMemsetAsync(dsum, 0, 4, stream);
  hipMemsetAsync(colsumL, 0, 4*256*4, stream);
  hipMemsetAsync(colssL,  0, 4*256*4, stream);

  k_pack_all<<<(pa.total+255)/256, 256, 0, stream>>>(pa);
  k_deg     <<<(NE+255)/256, 256, 0, stream>>>(edst, deg);
  k_logdeg  <<<(NN+255)/256, 256, 0, stream>>>(deg, logdeg, dsum);
  k_scalers <<<(NN+255)/256, 256, 0, stream>>>(logdeg, dsum, amp, att);
  k_scan1   <<<NB, 1024, 0, stream>>>(deg, rowptr, bsum);
  k_scan2   <<<1, 64, 0, stream>>>(bsum);
  k_scan3   <<<(NN+256)/256, 256, 0, stream>>>(rowptr, cursor, bsum);
  k_fill    <<<(NE+255)/256, 256, 0, stream>>>(esrc, edst, cursor, colidx);
  k_cvtx    <<<(NN*64+255)/256, 256, 0, stream>>>(x, hA);

  for(int l = 0; l < 4; l++){
    int d = din[l], o = dto[l];
    int nch = d / 64;
    int npb = (64 / (d >> 2)) * 4;          // nodes per block in k_agg4
    k_agg4<<<(NN+npb-1)/npb, 256, 0, stream>>>(hA, d, rowptr, colidx, aggs, aggN);
    dim3 g(o/64, (NN+127)/128);
    k_mfma_fused<<<g, 256, 0, stream>>>(hA, d, nch, aggs, amp, att, WpL[l], o, bb[l], hB);
    k_bn_stats<<<256, 256, 0, stream>>>(hB, o, colsumL + l*256, colssL + l*256);
    k_bn_apply<<<(NN*o+255)/256, 256, 0, stream>>>(hB, o, colsumL + l*256, colssL + l*256,
                                                   gm[l], bt[l], hA);
  }
  k_cls<<<(NN*16+255)/256, 256, 0, stream>>>(hA, Wc, bc, (float*)d_out);
}

// Round 10
// 813.865 us; speedup vs baseline: 1.7236x; 1.0033x over previous
//
#include <hip/hip_runtime.h>
#include <hip/hip_bf16.h>

#define NN 50000
#define NE 800000
#define EPSV 1e-5f
#define NB 49   // scan blocks: ceil(NN/1024)

typedef _Float16 h8 __attribute__((ext_vector_type(8)));
typedef _Float16 h4 __attribute__((ext_vector_type(4)));
typedef float    f4 __attribute__((ext_vector_type(4)));

// ---------------- graph preprocessing ----------------

__global__ void k_deg(const int* __restrict__ dst, int* __restrict__ deg){
  int e = blockIdx.x*blockDim.x + threadIdx.x;
  if(e < NE) atomicAdd(&deg[dst[e]], 1);
}

__global__ void k_logdeg(const int* __restrict__ deg, float* __restrict__ logdeg,
                         float* __restrict__ dsum){
  int i = blockIdx.x*blockDim.x + threadIdx.x;
  float v = 0.f;
  if(i < NN){ v = log1pf((float)deg[i]); logdeg[i] = v; }
  __shared__ float sh[256];
  sh[threadIdx.x] = v; __syncthreads();
  for(int off=128; off>0; off>>=1){
    if(threadIdx.x < off) sh[threadIdx.x] += sh[threadIdx.x+off];
    __syncthreads();
  }
  if(threadIdx.x == 0) atomicAdd(dsum, sh[0]);
}

__global__ void k_scalers(const float* __restrict__ logdeg, const float* __restrict__ dsum,
                          float* __restrict__ amp, float* __restrict__ att){
  int i = blockIdx.x*blockDim.x + threadIdx.x;
  if(i >= NN) return;
  float delta = dsum[0] / (float)NN;
  float ld = logdeg[i];
  amp[i] = ld / delta;
  att[i] = (ld > 0.f) ? (delta / fmaxf(ld, 1e-6f)) : 1.f;
}

// 3-phase parallel exclusive scan of deg -> rowptr (+cursor copy)
__global__ void k_scan1(const int* __restrict__ deg, int* __restrict__ rowptr,
                        int* __restrict__ bsum){
  __shared__ int buf[1024];
  int tid = threadIdx.x;
  int i = blockIdx.x*1024 + tid;
  int v = (i < NN) ? deg[i] : 0;
  buf[tid] = v; __syncthreads();
  for(int off=1; off<1024; off<<=1){
    int t = (tid >= off) ? buf[tid-off] : 0;
    __syncthreads();
    buf[tid] += t;
    __syncthreads();
  }
  if(i < NN) rowptr[i] = buf[tid] - v;
  if(tid == 1023) bsum[blockIdx.x] = buf[1023];
}

__global__ void k_scan2(int* __restrict__ bsum){
  if(threadIdx.x == 0){
    int s = 0;
    for(int b = 0; b < NB; b++){ int t = bsum[b]; bsum[b] = s; s += t; }
    bsum[NB] = s;
  }
}

__global__ void k_scan3(int* __restrict__ rowptr, int* __restrict__ cursor,
                        const int* __restrict__ bsum){
  int i = blockIdx.x*256 + threadIdx.x;
  if(i < NN){
    int v = rowptr[i] + bsum[i >> 10];
    rowptr[i] = v; cursor[i] = v;
  }
  if(i == NN) rowptr[NN] = bsum[NB];
}

__global__ void k_fill(const int* __restrict__ src, const int* __restrict__ dst,
                       int* __restrict__ cursor, int* __restrict__ colidx){
  int e = blockIdx.x*blockDim.x + threadIdx.x;
  if(e < NE){
    int pos = atomicAdd(&cursor[dst[e]], 1);
    colidx[pos] = src[e];
  }
}

__global__ void k_cvtx(const float* __restrict__ x, _Float16* __restrict__ hA){
  int i = blockIdx.x*256 + threadIdx.x;
  if(i < NN*64) hA[i] = (_Float16)x[i];
}

// ---------------- one-pass per-node aggregation (4 cols/lane, 8 B loads) ----------------
// aggs[chunk][n*256 + {0,64,128,192} + cl] = mean|min|max|std

__global__ __launch_bounds__(256) void k_agg4(
    const _Float16* __restrict__ h, int d,
    const int* __restrict__ rowptr, const int* __restrict__ colidx,
    _Float16* __restrict__ aggs, size_t aggN)
{
  int wv = threadIdx.x >> 6, lane = threadIdx.x & 63;
  int lpn = d >> 2;                 // lanes per node: 16/32/64
  int npw = 64 / lpn;               // nodes per wave: 4/2/1
  int n = blockIdx.x*(npw*4) + wv*npw + (lane / lpn);
  int c = (lane % lpn) * 4;         // 4 adjacent feature cols
  if(n >= NN) return;
  int beg = rowptr[n], end = rowptr[n+1];
  const _Float16* hp = h + c;

  float s0=0,s1=0,s2=0,s3=0, q0=0,q1=0,q2=0,q3=0;
  float mn0=INFINITY,mn1=INFINITY,mn2=INFINITY,mn3=INFINITY;
  float mx0=-INFINITY,mx1=-INFINITY,mx2=-INFINITY,mx3=-INFINITY;

#define ACC4(v) { float a0=(float)(v)[0],a1=(float)(v)[1],a2=(float)(v)[2],a3=(float)(v)[3]; \
    s0+=a0; q0+=a0*a0; mn0=fminf(mn0,a0); mx0=fmaxf(mx0,a0); \
    s1+=a1; q1+=a1*a1; mn1=fminf(mn1,a1); mx1=fmaxf(mx1,a1); \
    s2+=a2; q2+=a2*a2; mn2=fminf(mn2,a2); mx2=fmaxf(mx2,a2); \
    s3+=a3; q3+=a3*a3; mn3=fminf(mn3,a3); mx3=fmaxf(mx3,a3); }

  int e = beg;
  for(; e+4 <= end; e+=4){
    int i0=colidx[e], i1=colidx[e+1], i2=colidx[e+2], i3=colidx[e+3];
    h4 v0 = *(const h4*)(hp + (size_t)i0*d);
    h4 v1 = *(const h4*)(hp + (size_t)i1*d);
    h4 v2 = *(const h4*)(hp + (size_t)i2*d);
    h4 v3 = *(const h4*)(hp + (size_t)i3*d);
    ACC4(v0) ACC4(v1) ACC4(v2) ACC4(v3)
  }
  for(; e < end; e++){
    h4 v = *(const h4*)(hp + (size_t)colidx[e]*d);
    ACC4(v)
  }
#undef ACC4

  float cnt = (end>beg) ? (float)(end-beg) : 1.f;
  float me0=s0/cnt, me1=s1/cnt, me2=s2/cnt, me3=s3/cnt;
  float sd0 = sqrtf(fmaxf(q0/cnt - me0*me0, 0.f) + EPSV);
  float sd1 = sqrtf(fmaxf(q1/cnt - me1*me1, 0.f) + EPSV);
  float sd2 = sqrtf(fmaxf(q2/cnt - me2*me2, 0.f) + EPSV);
  float sd3 = sqrtf(fmaxf(q3/cnt - me3*me3, 0.f) + EPSV);
  if(end <= beg){ mn0=mn1=mn2=mn3=0.f; mx0=mx1=mx2=mx3=0.f; }

  _Float16* dst = aggs + (size_t)(c>>6)*aggN + (size_t)n*256 + (c & 63);
  h4 om = {(_Float16)me0,(_Float16)me1,(_Float16)me2,(_Float16)me3};
  h4 on = {(_Float16)mn0,(_Float16)mn1,(_Float16)mn2,(_Float16)mn3};
  h4 ox = {(_Float16)mx0,(_Float16)mx1,(_Float16)mx2,(_Float16)mx3};
  h4 os = {(_Float16)sd0,(_Float16)sd1,(_Float16)sd2,(_Float16)sd3};
  *(h4*)(dst)       = om;
  *(h4*)(dst + 64)  = on;
  *(h4*)(dst + 128) = ox;
  *(h4*)(dst + 192) = os;
}

// ---------------- fused W pre-pack (all layers/chunks, one kernel) ----------------
// Per chunk slab: Wp[kb=K/32][nt=o/16][lane=64][j=8]; row perm: k<64 -> j0+k ;
// [64,320)->(1+q)d+j0+r ; [320,576)->(5+q)d+j0+r ; [576,832)->(9+q)d+j0+r

struct PackJob { const float* W; _Float16* dst; int d, o, j0, start; };
struct PackArgs { PackJob job[9]; int total; };

__global__ void k_pack_all(PackArgs a){
  int idx = blockIdx.x*256 + threadIdx.x;
  if(idx >= a.total) return;
  int ji = 0;
  while(ji < 8 && idx >= a.job[ji+1].start) ji++;
  PackJob J = a.job[ji];
  int rel = idx - J.start;
  int j    = rel & 7;
  int lane = (rel >> 3) & 63;
  int rem  = rel >> 9;
  int ntiles = J.o >> 4;
  int kb = rem / ntiles;
  int nt = rem - kb*ntiles;
  int k = kb*32 + (lane>>4)*8 + j;
  int n = nt*16 + (lane&15);
  int srcrow;
  if(k < 64)       srcrow = J.j0 + k;
  else if(k < 320){ int t=k-64;  srcrow = (1+(t>>6))*J.d + J.j0 + (t&63); }
  else if(k < 576){ int t=k-320; srcrow = (5+(t>>6))*J.d + J.j0 + (t&63); }
  else            { int t=k-576; srcrow = (9+(t>>6))*J.d + J.j0 + (t&63); }
  J.dst[rel] = (_Float16)J.W[(size_t)srcrow*J.o + n];
}

// ---------------- fused MFMA layer GEMM, LDS-staged B ----------------
// One dispatch per layer; K (13d) accumulated in registers across chunks.
// Per chunk: A (18 frags) loaded direct-global up-front; B staged to LDS in
// two 52 KB half-phases (13 kb x 4 nn x 1 KB), consumed via ds_read_b128.
// Epilogue: +bias, ReLU, fp16 store.

__global__ __launch_bounds__(256, 3) void k_mfma_fused(
    const _Float16* __restrict__ hA, int d, int nch,
    const _Float16* __restrict__ aggs,          // [nch][NN][256]
    const float* __restrict__ amp, const float* __restrict__ att,
    const _Float16* __restrict__ Wp, int o,     // [nch][832*o]
    const float* __restrict__ bias,
    _Float16* __restrict__ out)                 // [NN][o], relu'd
{
  __shared__ _Float16 Bs[13*4*64*8];            // 52 KB -> 3 blocks/CU
  int tid  = threadIdx.x;
  int wv   = tid >> 6;
  int lane = tid & 63;
  int mi   = lane & 15;
  int q    = lane >> 4;
  int m0   = blockIdx.y * 128 + wv * 32;
  int c0   = blockIdx.x * 64;
  int ntiles = o >> 4;
  int nt0  = blockIdx.x * 4;

  int mrow[2];
  mrow[0] = min(m0 + mi,      NN-1);
  mrow[1] = min(m0 + 16 + mi, NN-1);
  _Float16 am16[2] = { (_Float16)amp[mrow[0]], (_Float16)amp[mrow[1]] };
  _Float16 at16[2] = { (_Float16)att[mrow[0]], (_Float16)att[mrow[1]] };
  const _Float16* hAb[2];
  const _Float16* agb[2];
  hAb[0] = hA + (size_t)mrow[0]*d + q*8;
  hAb[1] = hA + (size_t)mrow[1]*d + q*8;
  agb[0] = aggs + (size_t)mrow[0]*256 + q*8;
  agb[1] = aggs + (size_t)mrow[1]*256 + q*8;

  f4 acc[2][4] = {};
  const size_t aggN = (size_t)NN*256;

  for(int c = 0; c < nch; c++){
    const _Float16* Wpc = Wp + (size_t)c*832*o;

    // ---- A fragments for this chunk (global; latency hidden behind staging) ----
    h8 ax[2][2];     // [kb][t]   hA fragment
    h8 ag[8][2];     // [idx][t]  aggs fragment (shared by 3 scale variants)
    #pragma unroll
    for(int kb = 0; kb < 2; kb++)
      #pragma unroll
      for(int t = 0; t < 2; t++)
        ax[kb][t] = *(const h8*)(hAb[t] + c*64 + kb*32);
    #pragma unroll
    for(int idx = 0; idx < 8; idx++)
      #pragma unroll
      for(int t = 0; t < 2; t++)
        ag[idx][t] = *(const h8*)(agb[t] + (size_t)c*aggN + idx*32);

    #pragma unroll
    for(int hf = 0; hf < 2; hf++){
      // ---- stage 52 KB: kb in [hf*13, hf*13+13), wave wv copies nn=wv ----
      #pragma unroll
      for(int i = 0; i < 13; i++){
        h8 v = *(const h8*)(Wpc + (((size_t)(hf*13 + i)*ntiles + nt0 + wv)*64 + lane)*8);
        *(h8*)(&Bs[((i*4 + wv)*64 + lane)*8]) = v;
      }
      __syncthreads();

      // ---- consume: 13 kb x 4 nn x 2 t MFMAs, B via ds_read_b128 ----
      #pragma unroll
      for(int kbL = 0; kbL < 13; kbL++){
        int kb = hf*13 + kbL;
        h8 a0[2];
        if(kb < 2){
          a0[0] = ax[kb][0]; a0[1] = ax[kb][1];
        } else {
          int kb2 = kb - 2;
          int var = kb2 >> 3;         // 0=plain, 1=amp, 2=att
          int idx = kb2 & 7;
          if(var == 0){      a0[0] = ag[idx][0];            a0[1] = ag[idx][1]; }
          else if(var == 1){ a0[0] = ag[idx][0] * am16[0];  a0[1] = ag[idx][1] * am16[1]; }
          else{              a0[0] = ag[idx][0] * at16[0];  a0[1] = ag[idx][1] * at16[1]; }
        }
        #pragma unroll
        for(int nn = 0; nn < 4; nn++){
          h8 b = *(const h8*)(&Bs[((kbL*4 + nn)*64 + lane)*8]);
          acc[0][nn] = __builtin_amdgcn_mfma_f32_16x16x32_f16(a0[0], b, acc[0][nn], 0,0,0);
          acc[1][nn] = __builtin_amdgcn_mfma_f32_16x16x32_f16(a0[1], b, acc[1][nn], 0,0,0);
        }
      }
      __syncthreads();
    }
  }

  // ---- epilogue: +bias, ReLU, fp16 store. D col = lane&15, row = q*4+reg ----
  #pragma unroll
  for(int t = 0; t < 2; t++){
    #pragma unroll
    for(int nn = 0; nn < 4; nn++){
      int n = c0 + nn*16 + mi;
      float bv = bias[n];
      #pragma unroll
      for(int r = 0; r < 4; r++){
        int m = m0 + t*16 + q*4 + r;
        if(m < NN)
          out[(size_t)m*o + n] = (_Float16)fmaxf(bv + acc[t][nn][r], 0.f);
      }
    }
  }
}

// ---------------- BatchNorm (input already relu'd, fp16) ----------------

__global__ __launch_bounds__(256) void k_bn_stats(const _Float16* __restrict__ H, int dout,
                                                  float* __restrict__ colsum, float* __restrict__ colss){
  int tid = threadIdx.x;
  int gid = blockIdx.x*256 + tid;
  int stride = gridDim.x*256;
  int total = NN * dout;
  float s = 0.f, ss = 0.f;
  for(int i = gid; i < total; i += stride){
    float v = (float)H[i];
    s += v; ss += v*v;
  }
  __shared__ float shs[256], shss[256];
  shs[tid] = s; shss[tid] = ss;
  __syncthreads();
  if(tid < dout){
    float ts = 0.f, tss = 0.f;
    for(int i = tid; i < 256; i += dout){ ts += shs[i]; tss += shss[i]; }
    atomicAdd(&colsum[tid], ts);
    atomicAdd(&colss[tid], tss);
  }
}

__global__ void k_bn_apply(const _Float16* __restrict__ H, int dout,
                           const float* __restrict__ colsum, const float* __restrict__ colss,
                           const float* __restrict__ gamma, const float* __restrict__ beta,
                           _Float16* __restrict__ out){
  int i = blockIdx.x*blockDim.x + threadIdx.x;
  int total = NN * dout;
  if(i >= total) return;
  int c = i & (dout - 1);
  float mean = colsum[c] / (float)NN;
  float var  = colss[c] / (float)NN - mean*mean;
  float inv  = rsqrtf(fmaxf(var, 0.f) + EPSV);
  float v = (float)H[i];
  out[i] = (_Float16)((v - mean) * inv * gamma[c] + beta[c]);
}

// ---------------- classifier ----------------

__global__ __launch_bounds__(256) void k_cls(const _Float16* __restrict__ h,
    const float* __restrict__ Wc, const float* __restrict__ bc,
    float* __restrict__ out){
  __shared__ float w[640];
  __shared__ float bb[16];
  int tid = threadIdx.x;
  for(int i = tid; i < 640; i += 256) w[i] = Wc[i];
  if(tid < 10) bb[tid] = bc[tid];
  __syncthreads();
  int idx = blockIdx.x*256 + tid;
  int n = idx >> 4;
  int c = idx & 15;
  if(n < NN && c < 10){
    float acc = bb[c];
    const _Float16* hp = h + (size_t)n*64;
    #pragma unroll
    for(int k = 0; k < 64; k++) acc += (float)hp[k] * w[k*10 + c];
    out[(size_t)n*10 + c] = acc;
  }
}

// ---------------- launch ----------------

extern "C" void kernel_launch(void* const* d_in, const int* in_sizes, int n_in,
                              void* d_out, int out_size, void* d_ws, size_t ws_size,
                              hipStream_t stream){
  const float* x = (const float*)d_in[0];
  const int* edge = (const int*)d_in[1];
  const int* esrc = edge;
  const int* edst = edge + NE;
  const float* W[4]  = {(const float*)d_in[2],  (const float*)d_in[6],
                        (const float*)d_in[10], (const float*)d_in[14]};
  const float* bb[4] = {(const float*)d_in[3],  (const float*)d_in[7],
                        (const float*)d_in[11], (const float*)d_in[15]};
  const float* gm[4] = {(const float*)d_in[4],  (const float*)d_in[8],
                        (const float*)d_in[12], (const float*)d_in[16]};
  const float* bt[4] = {(const float*)d_in[5],  (const float*)d_in[9],
                        (const float*)d_in[13], (const float*)d_in[17]};
  const float* Wc = (const float*)d_in[18];
  const float* bc = (const float*)d_in[19];
  (void)in_sizes; (void)n_in; (void)out_size; (void)ws_size;

  // workspace carve (~158 MB; proven-safe envelope)
  char* p = (char*)d_ws;
  auto alloc = [&](size_t bytes)->char*{
    char* r = p; p += (bytes + 255) & ~(size_t)255; return r;
  };
  _Float16* hA   = (_Float16*)alloc((size_t)NN*256*2);   // 25.6 MB
  _Float16* hB   = (_Float16*)alloc((size_t)NN*256*2);   // 25.6 MB (relu'd, fp16)
  _Float16* aggs = (_Float16*)alloc((size_t)4*NN*256*2); // 102.4 MB: [chunk][N][256]
  int*   deg    = (int*)  alloc((size_t)NN*4);
  float* logdeg = (float*)alloc((size_t)NN*4);
  float* amp    = (float*)alloc((size_t)NN*4);
  float* att    = (float*)alloc((size_t)NN*4);
  int*   rowptr = (int*)  alloc((size_t)(NN+1)*4);
  int*   cursor = (int*)  alloc((size_t)NN*4);
  int*   colidx = (int*)  alloc((size_t)NE*4);
  int*   bsum   = (int*)  alloc((size_t)(NB+1)*4);
  float* colsumL= (float*)alloc(4*256*4);   // per-layer BN partials
  float* colssL = (float*)alloc(4*256*4);
  float* dsum   = (float*)alloc(256);

  const int din[4]  = {64, 128, 256, 128};
  const int dto[4]  = {128, 256, 128, 64};
  const size_t aggN = (size_t)NN*256;      // halves per chunk slab
  _Float16* WpL[4];
  PackArgs pa; int pj = 0, poff = 0;
  for(int l = 0; l < 4; l++){
    int nch = din[l]/64;
    WpL[l] = (_Float16*)alloc((size_t)nch*832*dto[l]*2);
    for(int c = 0; c < nch; c++){
      pa.job[pj] = { W[l], WpL[l] + (size_t)c*832*dto[l], din[l], dto[l], c*64, poff };
      poff += 832*dto[l]; pj++;
    }
  }
  pa.total = poff;

  hipMemsetAsync(deg, 0, (size_t)NN*4, stream);
  hipMemsetAsync(dsum, 0, 4, stream);
  hipMemsetAsync(colsumL, 0, 4*256*4, stream);
  hipMemsetAsync(colssL,  0, 4*256*4, stream);

  k_pack_all<<<(pa.total+255)/256, 256, 0, stream>>>(pa);
  k_deg     <<<(NE+255)/256, 256, 0, stream>>>(edst, deg);
  k_logdeg  <<<(NN+255)/256, 256, 0, stream>>>(deg, logdeg, dsum);
  k_scalers <<<(NN+255)/256, 256, 0, stream>>>(logdeg, dsum, amp, att);
  k_scan1   <<<NB, 1024, 0, stream>>>(deg, rowptr, bsum);
  k_scan2   <<<1, 64, 0, stream>>>(bsum);
  k_scan3   <<<(NN+256)/256, 256, 0, stream>>>(rowptr, cursor, bsum);
  k_fill    <<<(NE+255)/256, 256, 0, stream>>>(esrc, edst, cursor, colidx);
  k_cvtx    <<<(NN*64+255)/256, 256, 0, stream>>>(x, hA);

  for(int l = 0; l < 4; l++){
    int d = din[l], o = dto[l];
    int nch = d / 64;
    int npb = (64 / (d >> 2)) * 4;          // nodes per block in k_agg4
    k_agg4<<<(NN+npb-1)/npb, 256, 0, stream>>>(hA, d, rowptr, colidx, aggs, aggN);
    dim3 g(o/64, (NN+127)/128);
    k_mfma_fused<<<g, 256, 0, stream>>>(hA, d, nch, aggs, amp, att, WpL[l], o, bb[l], hB);
    k_bn_stats<<<256, 256, 0, stream>>>(hB, o, colsumL + l*256, colssL + l*256);
    k_bn_apply<<<(NN*o+255)/256, 256, 0, stream>>>(hB, o, colsumL + l*256, colssL + l*256,
                                                   gm[l], bt[l], hA);
  }
  k_cls<<<(NN*16+255)/256, 256, 0, stream>>>(hA, Wc, bc, (float*)d_out);
}